// Round 1
// baseline (673.442 us; speedup 1.0000x reference)
//
#include <hip/hip_runtime.h>
#include <cstdint>
#include <cstdio>

#define NODES 50000
#define FIN   128
#define NH1   4
#define C1CH  50
#define HID   200   // NH1*C1CH
#define FOUT  40

__device__ __forceinline__ float lrelu(float x) { return x > 0.f ? x : 0.2f * x; }

// ---------------- tiled fp32 GEMM: C[M,BN] = A[M,K] @ B[K,BN] ----------------
// 256 threads, BM=64 rows/block, full-width BN tile. thread = (rg 0..31, cg 0..7),
// rows {rg, rg+32}, cols [cg*CPT, cg*CPT+CPT)
template<int BN, int BK, int CPT>
__global__ void gemm_kernel(const float* __restrict__ A, const float* __restrict__ B,
                            float* __restrict__ C, int M, int K) {
    constexpr int BM = 64;
    __shared__ float As[BM][BK + 1];   // +1 pad: avoid 4-way bank conflict on column reads
    __shared__ float Bs[BK][BN];
    const int t  = threadIdx.x;
    const int cg = t & 7;
    const int rg = t >> 3;
    const int row0 = blockIdx.x * BM;

    float acc[2][CPT];
#pragma unroll
    for (int i = 0; i < 2; ++i)
#pragma unroll
        for (int j = 0; j < CPT; ++j) acc[i][j] = 0.f;

    for (int k0 = 0; k0 < K; k0 += BK) {
        for (int idx = t; idx < BM * BK; idx += 256) {
            int r = idx / BK, c = idx % BK;
            int gr = row0 + r;
            As[r][c] = (gr < M) ? A[(size_t)gr * K + k0 + c] : 0.f;
        }
        for (int idx = t; idx < BK * BN; idx += 256) {
            int r = idx / BN, c = idx % BN;
            Bs[r][c] = B[(size_t)(k0 + r) * BN + c];
        }
        __syncthreads();
#pragma unroll
        for (int kk = 0; kk < BK; ++kk) {
            float a0 = As[rg][kk];
            float a1 = As[rg + 32][kk];
#pragma unroll
            for (int j = 0; j < CPT; ++j) {
                float b = Bs[kk][cg * CPT + j];
                acc[0][j] += a0 * b;
                acc[1][j] += a1 * b;
            }
        }
        __syncthreads();
    }
#pragma unroll
    for (int i = 0; i < 2; ++i) {
        int gr = row0 + rg + i * 32;
        if (gr < M) {
#pragma unroll
            for (int j = 0; j < CPT; ++j)
                C[(size_t)gr * BN + cg * CPT + j] = acc[i][j];
        }
    }
}

// --------- per-node attention coefficients: a_src[n,h] = sum_c h[n,h*C+c]*w_src[h*C+c] ---------
template<int H, int C>
__global__ void att_scores(const float* __restrict__ h, const float* __restrict__ wsrc,
                           const float* __restrict__ wdst, float* __restrict__ asrc,
                           float* __restrict__ adst, int n) {
    int i = blockIdx.x * 256 + threadIdx.x;
    if (i >= n) return;
    constexpr int NC = H * C;
    const float4* row = reinterpret_cast<const float4*>(h + (size_t)i * NC);
    const float4* w4s = reinterpret_cast<const float4*>(wsrc);
    const float4* w4d = reinterpret_cast<const float4*>(wdst);
    float as[H] = {0.f};
    float ad[H] = {0.f};
#pragma unroll
    for (int q = 0; q < NC / 4; ++q) {
        float4 v = row[q], s4 = w4s[q], d4 = w4d[q];
        as[(4 * q + 0) / C] += v.x * s4.x;  ad[(4 * q + 0) / C] += v.x * d4.x;
        as[(4 * q + 1) / C] += v.y * s4.y;  ad[(4 * q + 1) / C] += v.y * d4.y;
        as[(4 * q + 2) / C] += v.z * s4.z;  ad[(4 * q + 2) / C] += v.z * d4.z;
        as[(4 * q + 3) / C] += v.w * s4.w;  ad[(4 * q + 3) / C] += v.w * d4.w;
    }
#pragma unroll
    for (int hh = 0; hh < H; ++hh) {
        asrc[(size_t)i * H + hh] = as[hh];
        adst[(size_t)i * H + hh] = ad[hh];
    }
}

// ---------------- CSR build ----------------
__global__ void hist_kernel(const int* __restrict__ dst, int* __restrict__ deg, int e) {
    int i = blockIdx.x * 256 + threadIdx.x;
    if (i < e) atomicAdd(&deg[dst[i]], 1);
}

__global__ void scan_kernel(const int* __restrict__ deg, int* __restrict__ rowptr,
                            int* __restrict__ cursor, int n) {
    __shared__ int wtot[16];
    __shared__ int s_carry;
    const int tid = threadIdx.x;           // 1024 threads
    const int lane = tid & 63, wid = tid >> 6;
    if (tid == 0) { s_carry = 0; rowptr[0] = 0; }
    __syncthreads();
    for (int base = 0; base < n; base += 1024) {
        int i = base + tid;
        int v = (i < n) ? deg[i] : 0;
        int x = v;
#pragma unroll
        for (int off = 1; off < 64; off <<= 1) {
            int up = __shfl_up(x, off);
            if (lane >= off) x += up;
        }
        if (lane == 63) wtot[wid] = x;
        __syncthreads();
        if (wid == 0) {
            int wv = (lane < 16) ? wtot[lane] : 0;
#pragma unroll
            for (int off = 1; off < 16; off <<= 1) {
                int up = __shfl_up(wv, off);
                if (lane >= off) wv += up;
            }
            if (lane < 16) wtot[lane] = wv;   // inclusive wave totals
        }
        __syncthreads();
        int woff = (wid == 0) ? 0 : wtot[wid - 1];
        int incl = x + woff + s_carry;
        if (i < n) { rowptr[i + 1] = incl; cursor[i] = incl - v; }
        __syncthreads();
        if (tid == 1023) s_carry = incl;
        __syncthreads();
    }
}

__global__ void scatter_kernel(const int* __restrict__ src, const int* __restrict__ dst,
                               int* __restrict__ cursor, int* __restrict__ csrc, int e) {
    int i = blockIdx.x * 256 + threadIdx.x;
    if (i < e) {
        int d = dst[i];
        int pos = atomicAdd(&cursor[d], 1);
        csrc[pos] = src[i];
    }
}

// ---------------- layer-1 aggregation: wave per node, fused bias+ELU ----------------
__global__ void gat_agg1(const float* __restrict__ h1, const float* __restrict__ asrc,
                         const float* __restrict__ adst, const int* __restrict__ rowptr,
                         const int* __restrict__ csrc, const float* __restrict__ b1,
                         float* __restrict__ out, int n) {
    int node = blockIdx.x * 4 + (threadIdx.x >> 6);
    if (node >= n) return;
    int lane = threadIdx.x & 63;
    int beg = rowptr[node], end = rowptr[node + 1];
    float4 ad = reinterpret_cast<const float4*>(adst)[node];

    float m0 = -1e30f, m1 = -1e30f, m2 = -1e30f, m3 = -1e30f;
    for (int j = beg; j < end; ++j) {
        int s = csrc[j];
        float4 as = reinterpret_cast<const float4*>(asrc)[s];
        m0 = fmaxf(m0, lrelu(as.x + ad.x));
        m1 = fmaxf(m1, lrelu(as.y + ad.y));
        m2 = fmaxf(m2, lrelu(as.z + ad.z));
        m3 = fmaxf(m3, lrelu(as.w + ad.w));
    }
    float s0 = 0.f, s1 = 0.f, s2 = 0.f, s3 = 0.f;
    float acc0 = 0.f, acc1 = 0.f, acc2 = 0.f, acc3 = 0.f;
    const bool act = lane < C1CH;
    for (int j = beg; j < end; ++j) {
        int s = csrc[j];
        float4 as = reinterpret_cast<const float4*>(asrc)[s];
        float p0 = __expf(lrelu(as.x + ad.x) - m0);
        float p1 = __expf(lrelu(as.y + ad.y) - m1);
        float p2 = __expf(lrelu(as.z + ad.z) - m2);
        float p3 = __expf(lrelu(as.w + ad.w) - m3);
        s0 += p0; s1 += p1; s2 += p2; s3 += p3;
        if (act) {
            const float* hr = h1 + (size_t)s * HID;
            acc0 += p0 * hr[lane];
            acc1 += p1 * hr[C1CH + lane];
            acc2 += p2 * hr[2 * C1CH + lane];
            acc3 += p3 * hr[3 * C1CH + lane];
        }
    }
    if (act) {
        float v0 = acc0 / (s0 + 1e-16f) + b1[lane];
        float v1 = acc1 / (s1 + 1e-16f) + b1[C1CH + lane];
        float v2 = acc2 / (s2 + 1e-16f) + b1[2 * C1CH + lane];
        float v3 = acc3 / (s3 + 1e-16f) + b1[3 * C1CH + lane];
        v0 = v0 > 0.f ? v0 : __expf(v0) - 1.f;
        v1 = v1 > 0.f ? v1 : __expf(v1) - 1.f;
        v2 = v2 > 0.f ? v2 : __expf(v2) - 1.f;
        v3 = v3 > 0.f ? v3 : __expf(v3) - 1.f;
        float* o = out + (size_t)node * HID;
        o[lane] = v0;
        o[C1CH + lane] = v1;
        o[2 * C1CH + lane] = v2;
        o[3 * C1CH + lane] = v3;
    }
}

// ---------------- layer-2 aggregation: wave per node, fused bias + log_softmax ----------------
__global__ void gat_agg2(const float* __restrict__ h2, const float* __restrict__ asrc,
                         const float* __restrict__ adst, const int* __restrict__ rowptr,
                         const int* __restrict__ csrc, const float* __restrict__ b2,
                         float* __restrict__ out, int n) {
    int node = blockIdx.x * 4 + (threadIdx.x >> 6);
    if (node >= n) return;
    int lane = threadIdx.x & 63;
    int beg = rowptr[node], end = rowptr[node + 1];
    float ad = adst[node];

    float m = -1e30f;
    for (int j = beg; j < end; ++j)
        m = fmaxf(m, lrelu(asrc[csrc[j]] + ad));

    float ssum = 0.f, acc = 0.f;
    const bool act = lane < FOUT;
    for (int j = beg; j < end; ++j) {
        int s = csrc[j];
        float p = __expf(lrelu(asrc[s] + ad) - m);
        ssum += p;
        if (act) acc += p * h2[(size_t)s * FOUT + lane];
    }
    float val = act ? (acc / (ssum + 1e-16f) + b2[lane]) : -1e30f;
    float mx = val;
#pragma unroll
    for (int off = 32; off >= 1; off >>= 1) mx = fmaxf(mx, __shfl_xor(mx, off));
    float ex = act ? __expf(val - mx) : 0.f;
    float z = ex;
#pragma unroll
    for (int off = 32; off >= 1; off >>= 1) z += __shfl_xor(z, off);
    if (act) out[(size_t)node * FOUT + lane] = val - mx - __logf(z);
}

extern "C" void kernel_launch(void* const* d_in, const int* in_sizes, int n_in,
                              void* d_out, int out_size, void* d_ws, size_t ws_size,
                              hipStream_t stream) {
    const float* x        = (const float*)d_in[0];
    const int*   esrc     = (const int*)d_in[1];
    const int*   edst     = (const int*)d_in[2];
    const float* W1       = (const float*)d_in[3];
    const float* att_src1 = (const float*)d_in[4];
    const float* att_dst1 = (const float*)d_in[5];
    const float* b1       = (const float*)d_in[6];
    const float* W2       = (const float*)d_in[7];
    const float* att_src2 = (const float*)d_in[8];
    const float* att_dst2 = (const float*)d_in[9];
    const float* b2       = (const float*)d_in[10];
    float* out = (float*)d_out;

    const int n = NODES;
    const int e = in_sizes[1];

    char* p = (char*)d_ws;
    auto alloc = [&](size_t bytes) -> char* {
        char* q = p;
        p += (bytes + 255) & ~(size_t)255;
        return q;
    };
    float* h1     = (float*)alloc((size_t)n * HID * 4);
    float* hcat   = (float*)alloc((size_t)n * HID * 4);
    float* h2     = (float*)alloc((size_t)n * FOUT * 4);
    float* as1    = (float*)alloc((size_t)n * NH1 * 4);
    float* ad1    = (float*)alloc((size_t)n * NH1 * 4);
    float* as2    = (float*)alloc((size_t)n * 4);
    float* ad2    = (float*)alloc((size_t)n * 4);
    int*   deg    = (int*)alloc((size_t)n * 4);
    int*   rowptr = (int*)alloc((size_t)(n + 1) * 4);
    int*   cursor = (int*)alloc((size_t)n * 4);
    int*   csrc   = (int*)alloc((size_t)e * 4);
    if ((size_t)(p - (char*)d_ws) > ws_size) {
        fprintf(stderr, "kernel_launch: ws too small (%zu needed, %zu given)\n",
                (size_t)(p - (char*)d_ws), ws_size);
        return;
    }

    // CSR build (edge list is fixed per call; rebuilt every call for determinism rules)
    hipMemsetAsync(deg, 0, (size_t)n * 4, stream);
    hist_kernel<<<(e + 255) / 256, 256, 0, stream>>>(edst, deg, e);
    scan_kernel<<<1, 1024, 0, stream>>>(deg, rowptr, cursor, n);
    scatter_kernel<<<(e + 255) / 256, 256, 0, stream>>>(esrc, edst, cursor, csrc, e);

    // layer 1
    gemm_kernel<HID, 16, 25><<<(n + 63) / 64, 256, 0, stream>>>(x, W1, h1, n, FIN);
    att_scores<NH1, C1CH><<<(n + 255) / 256, 256, 0, stream>>>(h1, att_src1, att_dst1, as1, ad1, n);
    gat_agg1<<<(n + 3) / 4, 256, 0, stream>>>(h1, as1, ad1, rowptr, csrc, b1, hcat, n);

    // layer 2
    gemm_kernel<FOUT, 20, 5><<<(n + 63) / 64, 256, 0, stream>>>(hcat, W2, h2, n, HID);
    att_scores<1, FOUT><<<(n + 255) / 256, 256, 0, stream>>>(h2, att_src2, att_dst2, as2, ad2, n);
    gat_agg2<<<(n + 3) / 4, 256, 0, stream>>>(h2, as2, ad2, rowptr, csrc, b2, out, n);
}

// Round 2
// 446.876 us; speedup vs baseline: 1.5070x; 1.5070x over previous
//
#include <hip/hip_runtime.h>
#include <cstdint>
#include <cstdio>

#define NODES 50000
#define FIN   128
#define NH1   4
#define C1CH  50
#define HID   200   // NH1*C1CH
#define FOUT  40

__device__ __forceinline__ float lrelu(float x) { return x > 0.f ? x : 0.2f * x; }
__device__ __forceinline__ float b2f(unsigned short u) {
    return __uint_as_float(((unsigned int)u) << 16);
}
__device__ __forceinline__ unsigned short f2b(float f) {
    unsigned int x = __float_as_uint(f);
    return (unsigned short)((x + 0x7fffu + ((x >> 16) & 1u)) >> 16);  // RNE
}

// ---------------- GEMM1 fused: h1 = x@W1 (fp32 math), writes bf16 h1 + att scores ----------------
// 256 thr, BM=128 rows, BN=200 full width. thread=(rg 0..31, cg 0..7): rows rg+32i, cols cg*25..+24.
// Head of col block cg = cg/2 (25*2 = 50 cols/head) -> att reduce is one shfl_xor(1).
__global__ __launch_bounds__(256) void gemm1_fused(
    const float* __restrict__ A, const float* __restrict__ B,
    const float* __restrict__ wsrc, const float* __restrict__ wdst,
    unsigned short* __restrict__ Hb, float* __restrict__ as1, float* __restrict__ ad1, int M) {
    constexpr int BM = 128, BK = 16, BN = HID, CPT = 25;
    __shared__ float As[BM][BK + 1];
    __shared__ float Bs[BK][BN];
    __shared__ float wsS[BN], wdS[BN];
    const int t = threadIdx.x, cg = t & 7, rg = t >> 3;
    const int row0 = blockIdx.x * BM;
    if (t < BN) { wsS[t] = wsrc[t]; wdS[t] = wdst[t]; }

    float acc[4][CPT];
#pragma unroll
    for (int i = 0; i < 4; ++i)
#pragma unroll
        for (int j = 0; j < CPT; ++j) acc[i][j] = 0.f;

    for (int k0 = 0; k0 < FIN; k0 += BK) {
#pragma unroll
        for (int idx = t; idx < BM * BK; idx += 256) {
            int r = idx >> 4, c = idx & 15;
            int gr = row0 + r;
            As[r][c] = (gr < M) ? A[(size_t)gr * FIN + k0 + c] : 0.f;
        }
        for (int idx = t; idx < BK * BN; idx += 256) {
            int r = idx / BN, c = idx % BN;
            Bs[r][c] = B[(size_t)(k0 + r) * BN + c];
        }
        __syncthreads();
#pragma unroll
        for (int kk = 0; kk < BK; ++kk) {
            float a0 = As[rg][kk], a1 = As[rg + 32][kk], a2 = As[rg + 64][kk], a3 = As[rg + 96][kk];
#pragma unroll
            for (int j = 0; j < CPT; ++j) {
                float b = Bs[kk][cg * CPT + j];
                acc[0][j] += a0 * b; acc[1][j] += a1 * b;
                acc[2][j] += a2 * b; acc[3][j] += a3 * b;
            }
        }
        __syncthreads();
    }
    const int col0 = cg * CPT;
#pragma unroll
    for (int i = 0; i < 4; ++i) {
        int gr = row0 + rg + 32 * i;
        if (gr >= M) continue;
        float ps = 0.f, pd = 0.f;
#pragma unroll
        for (int j = 0; j < CPT; ++j) {
            ps += acc[i][j] * wsS[col0 + j];
            pd += acc[i][j] * wdS[col0 + j];
        }
        float ps2 = ps + __shfl_xor(ps, 1);
        float pd2 = pd + __shfl_xor(pd, 1);
        if ((cg & 1) == 0) {
            as1[(size_t)gr * NH1 + (cg >> 1)] = ps2;
            ad1[(size_t)gr * NH1 + (cg >> 1)] = pd2;
        }
        unsigned short* hr = Hb + (size_t)gr * BN + col0;
#pragma unroll
        for (int j = 0; j < CPT; ++j) hr[j] = f2b(acc[i][j]);
    }
}

// ---------------- GEMM2 fused: h2 = hcat@W2, writes bf16 h2 + att scores (1 head) ----------------
__global__ __launch_bounds__(256) void gemm2_fused(
    const float* __restrict__ A, const float* __restrict__ B,
    const float* __restrict__ wsrc, const float* __restrict__ wdst,
    unsigned short* __restrict__ Hb, float* __restrict__ as2, float* __restrict__ ad2, int M) {
    constexpr int BM = 128, BK = 40, BN = FOUT, CPT = 5;
    __shared__ float As[BM][BK + 1];
    __shared__ float Bs[BK][BN];
    __shared__ float wsS[BN], wdS[BN];
    const int t = threadIdx.x, cg = t & 7, rg = t >> 3;
    const int row0 = blockIdx.x * BM;
    if (t < BN) { wsS[t] = wsrc[t]; wdS[t] = wdst[t]; }

    float acc[4][CPT];
#pragma unroll
    for (int i = 0; i < 4; ++i)
#pragma unroll
        for (int j = 0; j < CPT; ++j) acc[i][j] = 0.f;

    for (int k0 = 0; k0 < HID; k0 += BK) {
        for (int idx = t; idx < BM * BK; idx += 256) {
            int r = idx / BK, c = idx % BK;
            int gr = row0 + r;
            As[r][c] = (gr < M) ? A[(size_t)gr * HID + k0 + c] : 0.f;
        }
        for (int idx = t; idx < BK * BN; idx += 256) {
            int r = idx / BN, c = idx % BN;
            Bs[r][c] = B[(size_t)(k0 + r) * BN + c];
        }
        __syncthreads();
#pragma unroll
        for (int kk = 0; kk < BK; ++kk) {
            float a0 = As[rg][kk], a1 = As[rg + 32][kk], a2 = As[rg + 64][kk], a3 = As[rg + 96][kk];
#pragma unroll
            for (int j = 0; j < CPT; ++j) {
                float b = Bs[kk][cg * CPT + j];
                acc[0][j] += a0 * b; acc[1][j] += a1 * b;
                acc[2][j] += a2 * b; acc[3][j] += a3 * b;
            }
        }
        __syncthreads();
    }
    const int col0 = cg * CPT;
#pragma unroll
    for (int i = 0; i < 4; ++i) {
        int gr = row0 + rg + 32 * i;
        if (gr >= M) continue;
        float ps = 0.f, pd = 0.f;
#pragma unroll
        for (int j = 0; j < CPT; ++j) {
            ps += acc[i][j] * wsS[col0 + j];
            pd += acc[i][j] * wdS[col0 + j];
        }
#pragma unroll
        for (int off = 1; off < 8; off <<= 1) {
            ps += __shfl_xor(ps, off);
            pd += __shfl_xor(pd, off);
        }
        if (cg == 0) { as2[gr] = ps; ad2[gr] = pd; }
        unsigned short* hr = Hb + (size_t)gr * BN + col0;
#pragma unroll
        for (int j = 0; j < CPT; ++j) hr[j] = f2b(acc[i][j]);
    }
}

// ---------------- CSR build ----------------
__global__ void hist_kernel(const int* __restrict__ dst, int* __restrict__ deg, int e) {
    int i = blockIdx.x * 256 + threadIdx.x;
    if (i < e) atomicAdd(&deg[dst[i]], 1);
}

__global__ __launch_bounds__(1024) void blockscan_kernel(const int* __restrict__ deg,
                                                         int* __restrict__ incl,
                                                         int* __restrict__ bsum, int n) {
    __shared__ int wtot[16];
    const int tid = threadIdx.x, lane = tid & 63, wid = tid >> 6;
    int i = blockIdx.x * 1024 + tid;
    int v = (i < n) ? deg[i] : 0;
    int x = v;
#pragma unroll
    for (int off = 1; off < 64; off <<= 1) {
        int up = __shfl_up(x, off);
        if (lane >= off) x += up;
    }
    if (lane == 63) wtot[wid] = x;
    __syncthreads();
    if (wid == 0) {
        int wv = (lane < 16) ? wtot[lane] : 0;
#pragma unroll
        for (int off = 1; off < 16; off <<= 1) {
            int up = __shfl_up(wv, off);
            if (lane >= off) wv += up;
        }
        if (lane < 16) wtot[lane] = wv;
    }
    __syncthreads();
    int xi = x + (wid ? wtot[wid - 1] : 0);
    if (i < n) incl[i] = xi;
    if (tid == 1023) bsum[blockIdx.x] = xi;
}

__global__ void sumscan_kernel(const int* __restrict__ bsum, int* __restrict__ boffs, int nb) {
    int lane = threadIdx.x;
    int v = (lane < nb) ? bsum[lane] : 0;
    int x = v;
#pragma unroll
    for (int off = 1; off < 64; off <<= 1) {
        int up = __shfl_up(x, off);
        if (lane >= off) x += up;
    }
    if (lane < nb) boffs[lane] = x - v;   // exclusive
}

__global__ void applyscan_kernel(const int* __restrict__ incl, const int* __restrict__ boffs,
                                 const int* __restrict__ deg, int* __restrict__ rowptr,
                                 int* __restrict__ cursor, int n) {
    int i = blockIdx.x * 256 + threadIdx.x;
    if (i < n) {
        int val = incl[i] + boffs[i >> 10];
        rowptr[i + 1] = val;
        cursor[i] = val - deg[i];
    }
    if (i == 0) rowptr[0] = 0;
}

__global__ void scatter_kernel(const int* __restrict__ src, const int* __restrict__ dst,
                               int* __restrict__ cursor, int* __restrict__ csrc, int e) {
    int i = blockIdx.x * 256 + threadIdx.x;
    if (i < e) {
        int d = dst[i];
        int pos = atomicAdd(&cursor[d], 1);
        csrc[pos] = src[i];
    }
}

// ------- layer-1 aggregation: wave/node, single pass (softmax shift-invariance, m=0) -------
#define SEL4(hd, q0, q1, q2, q3) ((hd) == 0 ? (q0) : (hd) == 1 ? (q1) : (hd) == 2 ? (q2) : (q3))

__global__ __launch_bounds__(256) void gat_agg1(
    const unsigned short* __restrict__ Hb, const float* __restrict__ asrc,
    const float* __restrict__ adst, const int* __restrict__ rowptr,
    const int* __restrict__ csrc, const float* __restrict__ b1,
    float* __restrict__ outp, int n) {
    int node = blockIdx.x * 4 + (threadIdx.x >> 6);
    if (node >= n) return;
    const int lane = threadIdx.x & 63;
    const int beg = rowptr[node], end = rowptr[node + 1];
    const float4 ad = reinterpret_cast<const float4*>(adst)[node];
    const bool act = lane < C1CH;
    const int ch0 = lane * 4;
    const int hd0 = ch0 / C1CH, hd1 = (ch0 + 1) / C1CH, hd2 = (ch0 + 2) / C1CH, hd3 = (ch0 + 3) / C1CH;

    float s0 = 0.f, s1 = 0.f, s2 = 0.f, s3 = 0.f;
    float a0 = 0.f, a1 = 0.f, a2 = 0.f, a3 = 0.f;
    const float4* as4 = reinterpret_cast<const float4*>(asrc);

    int j = beg;
    for (; j + 2 <= end; j += 2) {
        int sA = csrc[j], sB = csrc[j + 1];
        float4 avA = as4[sA], avB = as4[sB];
        ushort4 hA, hB;
        if (act) {
            hA = *reinterpret_cast<const ushort4*>(Hb + (size_t)sA * HID + ch0);
            hB = *reinterpret_cast<const ushort4*>(Hb + (size_t)sB * HID + ch0);
        }
        float pA0 = __expf(lrelu(avA.x + ad.x)), pA1 = __expf(lrelu(avA.y + ad.y));
        float pA2 = __expf(lrelu(avA.z + ad.z)), pA3 = __expf(lrelu(avA.w + ad.w));
        float pB0 = __expf(lrelu(avB.x + ad.x)), pB1 = __expf(lrelu(avB.y + ad.y));
        float pB2 = __expf(lrelu(avB.z + ad.z)), pB3 = __expf(lrelu(avB.w + ad.w));
        s0 += pA0 + pB0; s1 += pA1 + pB1; s2 += pA2 + pB2; s3 += pA3 + pB3;
        if (act) {
            a0 += SEL4(hd0, pA0, pA1, pA2, pA3) * b2f(hA.x) + SEL4(hd0, pB0, pB1, pB2, pB3) * b2f(hB.x);
            a1 += SEL4(hd1, pA0, pA1, pA2, pA3) * b2f(hA.y) + SEL4(hd1, pB0, pB1, pB2, pB3) * b2f(hB.y);
            a2 += SEL4(hd2, pA0, pA1, pA2, pA3) * b2f(hA.z) + SEL4(hd2, pB0, pB1, pB2, pB3) * b2f(hB.z);
            a3 += SEL4(hd3, pA0, pA1, pA2, pA3) * b2f(hA.w) + SEL4(hd3, pB0, pB1, pB2, pB3) * b2f(hB.w);
        }
    }
    if (j < end) {
        int sA = csrc[j];
        float4 avA = as4[sA];
        float pA0 = __expf(lrelu(avA.x + ad.x)), pA1 = __expf(lrelu(avA.y + ad.y));
        float pA2 = __expf(lrelu(avA.z + ad.z)), pA3 = __expf(lrelu(avA.w + ad.w));
        s0 += pA0; s1 += pA1; s2 += pA2; s3 += pA3;
        if (act) {
            ushort4 hA = *reinterpret_cast<const ushort4*>(Hb + (size_t)sA * HID + ch0);
            a0 += SEL4(hd0, pA0, pA1, pA2, pA3) * b2f(hA.x);
            a1 += SEL4(hd1, pA0, pA1, pA2, pA3) * b2f(hA.y);
            a2 += SEL4(hd2, pA0, pA1, pA2, pA3) * b2f(hA.z);
            a3 += SEL4(hd3, pA0, pA1, pA2, pA3) * b2f(hA.w);
        }
    }
    if (act) {
        float4 bv = reinterpret_cast<const float4*>(b1)[lane];
        float q0 = SEL4(hd0, s0, s1, s2, s3), q1 = SEL4(hd1, s0, s1, s2, s3);
        float q2 = SEL4(hd2, s0, s1, s2, s3), q3 = SEL4(hd3, s0, s1, s2, s3);
        float v0 = a0 / (q0 + 1e-16f) + bv.x;
        float v1 = a1 / (q1 + 1e-16f) + bv.y;
        float v2 = a2 / (q2 + 1e-16f) + bv.z;
        float v3 = a3 / (q3 + 1e-16f) + bv.w;
        v0 = v0 > 0.f ? v0 : __expf(v0) - 1.f;
        v1 = v1 > 0.f ? v1 : __expf(v1) - 1.f;
        v2 = v2 > 0.f ? v2 : __expf(v2) - 1.f;
        v3 = v3 > 0.f ? v3 : __expf(v3) - 1.f;
        reinterpret_cast<float4*>(outp)[(size_t)node * (HID / 4) + lane] = make_float4(v0, v1, v2, v3);
    }
}

// ------- layer-2 aggregation: wave/node, single pass, fused bias + log_softmax -------
__global__ __launch_bounds__(256) void gat_agg2(
    const unsigned short* __restrict__ Hb, const float* __restrict__ asrc,
    const float* __restrict__ adst, const int* __restrict__ rowptr,
    const int* __restrict__ csrc, const float* __restrict__ b2,
    float* __restrict__ outp, int n) {
    int node = blockIdx.x * 4 + (threadIdx.x >> 6);
    if (node >= n) return;
    const int lane = threadIdx.x & 63;
    const int beg = rowptr[node], end = rowptr[node + 1];
    const float ad = adst[node];
    const bool act = lane < FOUT;

    float ssum = 0.f, acc = 0.f;
    int j = beg;
    for (; j + 2 <= end; j += 2) {
        int sA = csrc[j], sB = csrc[j + 1];
        float eA = asrc[sA], eB = asrc[sB];
        unsigned short hA = 0, hB = 0;
        if (act) {
            hA = Hb[(size_t)sA * FOUT + lane];
            hB = Hb[(size_t)sB * FOUT + lane];
        }
        float pA = __expf(lrelu(eA + ad));
        float pB = __expf(lrelu(eB + ad));
        ssum += pA + pB;
        if (act) acc += pA * b2f(hA) + pB * b2f(hB);
    }
    if (j < end) {
        int sA = csrc[j];
        float pA = __expf(lrelu(asrc[sA] + ad));
        ssum += pA;
        if (act) acc += pA * b2f(Hb[(size_t)sA * FOUT + lane]);
    }
    float val = act ? (acc / (ssum + 1e-16f) + b2[lane]) : -1e30f;
    float mx = val;
#pragma unroll
    for (int off = 32; off >= 1; off >>= 1) mx = fmaxf(mx, __shfl_xor(mx, off));
    float ex = act ? __expf(val - mx) : 0.f;
    float z = ex;
#pragma unroll
    for (int off = 32; off >= 1; off >>= 1) z += __shfl_xor(z, off);
    if (act) outp[(size_t)node * FOUT + lane] = val - mx - __logf(z);
}

extern "C" void kernel_launch(void* const* d_in, const int* in_sizes, int n_in,
                              void* d_out, int out_size, void* d_ws, size_t ws_size,
                              hipStream_t stream) {
    const float* x        = (const float*)d_in[0];
    const int*   esrc     = (const int*)d_in[1];
    const int*   edst     = (const int*)d_in[2];
    const float* W1       = (const float*)d_in[3];
    const float* att_src1 = (const float*)d_in[4];
    const float* att_dst1 = (const float*)d_in[5];
    const float* b1       = (const float*)d_in[6];
    const float* W2       = (const float*)d_in[7];
    const float* att_src2 = (const float*)d_in[8];
    const float* att_dst2 = (const float*)d_in[9];
    const float* b2       = (const float*)d_in[10];
    float* out = (float*)d_out;

    const int n = NODES;
    const int e = in_sizes[1];
    const int nb = (n + 1023) / 1024;

    char* p = (char*)d_ws;
    auto alloc = [&](size_t bytes) -> char* {
        char* q = p;
        p += (bytes + 255) & ~(size_t)255;
        return q;
    };
    unsigned short* h1b  = (unsigned short*)alloc((size_t)n * HID * 2);
    float*          hcat = (float*)alloc((size_t)n * HID * 4);
    unsigned short* h2b  = (unsigned short*)alloc((size_t)n * FOUT * 2);
    float* as1    = (float*)alloc((size_t)n * NH1 * 4);
    float* ad1    = (float*)alloc((size_t)n * NH1 * 4);
    float* as2    = (float*)alloc((size_t)n * 4);
    float* ad2    = (float*)alloc((size_t)n * 4);
    int*   deg    = (int*)alloc((size_t)n * 4);
    int*   incl   = (int*)alloc((size_t)n * 4);
    int*   rowptr = (int*)alloc((size_t)(n + 1) * 4);
    int*   cursor = (int*)alloc((size_t)n * 4);
    int*   csrc   = (int*)alloc((size_t)e * 4);
    int*   bsum   = (int*)alloc((size_t)nb * 4);
    int*   boffs  = (int*)alloc((size_t)nb * 4);
    if ((size_t)(p - (char*)d_ws) > ws_size) {
        fprintf(stderr, "kernel_launch: ws too small (%zu needed, %zu given)\n",
                (size_t)(p - (char*)d_ws), ws_size);
        return;
    }

    // CSR build
    hipMemsetAsync(deg, 0, (size_t)n * 4, stream);
    hist_kernel<<<(e + 255) / 256, 256, 0, stream>>>(edst, deg, e);
    blockscan_kernel<<<nb, 1024, 0, stream>>>(deg, incl, bsum, n);
    sumscan_kernel<<<1, 64, 0, stream>>>(bsum, boffs, nb);
    applyscan_kernel<<<(n + 255) / 256, 256, 0, stream>>>(incl, boffs, deg, rowptr, cursor, n);
    scatter_kernel<<<(e + 255) / 256, 256, 0, stream>>>(esrc, edst, cursor, csrc, e);

    // layer 1
    gemm1_fused<<<(n + 127) / 128, 256, 0, stream>>>(x, W1, att_src1, att_dst1, h1b, as1, ad1, n);
    gat_agg1<<<(n + 3) / 4, 256, 0, stream>>>(h1b, as1, ad1, rowptr, csrc, b1, hcat, n);

    // layer 2
    gemm2_fused<<<(n + 127) / 128, 256, 0, stream>>>(hcat, W2, att_src2, att_dst2, h2b, as2, ad2, n);
    gat_agg2<<<(n + 3) / 4, 256, 0, stream>>>(h2b, as2, ad2, rowptr, csrc, b2, out, n);
}

// Round 4
// 381.447 us; speedup vs baseline: 1.7655x; 1.1715x over previous
//
#include <hip/hip_runtime.h>
#include <cstdint>
#include <cstdio>

#define NODES 50000
#define FIN   128
#define NH1   4
#define C1CH  50
#define HID   200   // NH1*C1CH
#define KPAD2 224   // HID padded to multiple of 32 for MFMA K-steps
#define FOUT  40
#define NPAD1 208   // HID padded to multiple of 16
#define NPAD2 48    // FOUT padded to multiple of 16

typedef __attribute__((ext_vector_type(8))) short bf16x8;
typedef __attribute__((ext_vector_type(4))) float f32x4;

__device__ __forceinline__ float lrelu(float x) { return x > 0.f ? x : 0.2f * x; }
__device__ __forceinline__ float b2f(unsigned short u) {
    return __uint_as_float(((unsigned int)u) << 16);
}
__device__ __forceinline__ unsigned short f2b(float f) {
    unsigned int x = __float_as_uint(f);
    return (unsigned short)((x + 0x7fffu + ((x >> 16) & 1u)) >> 16);  // RNE
}
// split v into hi (bf16) + lo (bf16 of residual); hi+lo carries ~17 mantissa bits
__device__ __forceinline__ void split_bf16(float v, unsigned short& hi, unsigned short& lo) {
    hi = f2b(v);
    lo = f2b(v - b2f(hi));
}

// ---------------- weight prep: transpose + hi/lo split ----------------
// W1 [128][200] fp32 -> W1^T hi/lo bf16 [208][128] (rows 200..207 zero)
__global__ void prep_w1(const float* __restrict__ W1, unsigned short* __restrict__ hi,
                        unsigned short* __restrict__ lo) {
    int i = blockIdx.x * 256 + threadIdx.x;
    if (i >= NPAD1 * FIN) return;
    int n = i >> 7, k = i & 127;
    float v = (n < HID) ? W1[(size_t)k * HID + n] : 0.f;
    unsigned short h, l;
    split_bf16(v, h, l);
    hi[i] = h; lo[i] = l;
}

// W2 [200][40] fp32 -> W2^T hi/lo bf16 [48][224] (zero padded both dims)
__global__ void prep_w2(const float* __restrict__ W2, unsigned short* __restrict__ hi,
                        unsigned short* __restrict__ lo) {
    int i = blockIdx.x * 256 + threadIdx.x;
    if (i >= NPAD2 * KPAD2) return;
    int n = i / KPAD2, k = i % KPAD2;
    float v = (n < FOUT && k < HID) ? W2[(size_t)k * FOUT + n] : 0.f;
    unsigned short h, l;
    split_bf16(v, h, l);
    hi[i] = h; lo[i] = l;
}

// ---------------- GEMM1 (split-bf16 MFMA, no LDS): h1 = x@W1, fused att1 ----------------
// 4 waves/block, wave = 16 rows x 208 cols (13 N-tiles), K=128 (4 K-steps), 3 MFMA/tile.
__global__ __launch_bounds__(256) void gemm1_mfma(
    const float* __restrict__ x, const unsigned short* __restrict__ w1hi,
    const unsigned short* __restrict__ w1lo,
    const float* __restrict__ wsrc, const float* __restrict__ wdst,
    unsigned short* __restrict__ Hb, float* __restrict__ as1, float* __restrict__ ad1, int M) {
    const int wid = threadIdx.x >> 6;
    const int l = threadIdx.x & 63, lr = l & 15, lg = l >> 4;
    const int row0 = blockIdx.x * 64 + wid * 16;

    int arow = row0 + lr; arow = arow < M ? arow : M - 1;
    const float* xrow = x + (size_t)arow * FIN + lg * 8;
    bf16x8 ahi[4], alo[4];
#pragma unroll
    for (int ks = 0; ks < 4; ++ks) {
        float4 f0 = *reinterpret_cast<const float4*>(xrow + ks * 32);
        float4 f1 = *reinterpret_cast<const float4*>(xrow + ks * 32 + 4);
        float fv[8] = {f0.x, f0.y, f0.z, f0.w, f1.x, f1.y, f1.z, f1.w};
#pragma unroll
        for (int q = 0; q < 8; ++q) {
            unsigned short h, lo;
            split_bf16(fv[q], h, lo);
            ahi[ks][q] = (short)h;
            alo[ks][q] = (short)lo;
        }
    }

    f32x4 acc[13];
#pragma unroll
    for (int nt = 0; nt < 13; ++nt) acc[nt] = {0.f, 0.f, 0.f, 0.f};

#pragma unroll
    for (int ks = 0; ks < 4; ++ks) {
#pragma unroll
        for (int nt = 0; nt < 13; ++nt) {
            size_t boff = (size_t)(nt * 16 + lr) * FIN + ks * 32 + lg * 8;
            bf16x8 bhi = *reinterpret_cast<const bf16x8*>(w1hi + boff);
            bf16x8 blo = *reinterpret_cast<const bf16x8*>(w1lo + boff);
            acc[nt] = __builtin_amdgcn_mfma_f32_16x16x32_bf16(ahi[ks], bhi, acc[nt], 0, 0, 0);
            acc[nt] = __builtin_amdgcn_mfma_f32_16x16x32_bf16(alo[ks], bhi, acc[nt], 0, 0, 0);
            acc[nt] = __builtin_amdgcn_mfma_f32_16x16x32_bf16(ahi[ks], blo, acc[nt], 0, 0, 0);
        }
    }

    // fused att1: per-lane head-segmented partial dot, 16-lane reduce
    float phs[4][4], phd[4][4];   // [reg][head]
#pragma unroll
    for (int r = 0; r < 4; ++r)
#pragma unroll
        for (int h = 0; h < 4; ++h) { phs[r][h] = 0.f; phd[r][h] = 0.f; }

#pragma unroll
    for (int nt = 0; nt < 13; ++nt) {
        int col = nt * 16 + lr;
        int cc = col < HID ? col : 0;
        float wsv = wsrc[cc]; wsv = col < HID ? wsv : 0.f;
        float wdv = wdst[cc]; wdv = col < HID ? wdv : 0.f;
        const int h_lo = (nt * 16) / C1CH;                 // compile-time after unroll
        const int splitc = (h_lo + 1) * C1CH - nt * 16;    // lanes lr<splitc -> h_lo
#pragma unroll
        for (int r = 0; r < 4; ++r) {
            float ps = acc[nt][r] * wsv, pd = acc[nt][r] * wdv;
            if (splitc >= 16) { phs[r][h_lo] += ps; phd[r][h_lo] += pd; }
            else if (h_lo < 3) {
                if (lr < splitc) { phs[r][h_lo] += ps; phd[r][h_lo] += pd; }
                else             { phs[r][h_lo + 1] += ps; phd[r][h_lo + 1] += pd; }
            } else { phs[r][3] += ps; phd[r][3] += pd; }   // nt=12 tail (cols>=200 are zero)
        }
    }

#pragma unroll
    for (int r = 0; r < 4; ++r) {
#pragma unroll
        for (int h = 0; h < 4; ++h) {
#pragma unroll
            for (int off = 1; off < 16; off <<= 1) {
                phs[r][h] += __shfl_xor(phs[r][h], off);
                phd[r][h] += __shfl_xor(phd[r][h], off);
            }
        }
        int row = row0 + lg * 4 + r;
        if (lr == 0 && row < M) {
            reinterpret_cast<float4*>(as1)[row] = make_float4(phs[r][0], phs[r][1], phs[r][2], phs[r][3]);
            reinterpret_cast<float4*>(ad1)[row] = make_float4(phd[r][0], phd[r][1], phd[r][2], phd[r][3]);
        }
    }

    // bf16 H store (gather operand for agg1)
#pragma unroll
    for (int nt = 0; nt < 13; ++nt) {
        int col = nt * 16 + lr;
        if (col < HID) {
#pragma unroll
            for (int r = 0; r < 4; ++r) {
                int row = row0 + lg * 4 + r;
                if (row < M) Hb[(size_t)row * HID + col] = f2b(acc[nt][r]);
            }
        }
    }
}

// ---------------- GEMM2 (split-bf16 MFMA, no LDS): h2 = hcat@W2, fused att2 ----------------
__global__ __launch_bounds__(256) void gemm2_mfma(
    const float* __restrict__ hcat, const unsigned short* __restrict__ w2hi,
    const unsigned short* __restrict__ w2lo,
    const float* __restrict__ wsrc, const float* __restrict__ wdst,
    unsigned short* __restrict__ Hb, float* __restrict__ as2, float* __restrict__ ad2, int M) {
    const int wid = threadIdx.x >> 6;
    const int l = threadIdx.x & 63, lr = l & 15, lg = l >> 4;
    const int row0 = blockIdx.x * 64 + wid * 16;

    int arow = row0 + lr; arow = arow < M ? arow : M - 1;
    const float* hrow = hcat + (size_t)arow * KPAD2 + lg * 8;
    bf16x8 ahi[7], alo[7];
#pragma unroll
    for (int ks = 0; ks < 7; ++ks) {
        float4 f0 = *reinterpret_cast<const float4*>(hrow + ks * 32);
        float4 f1 = *reinterpret_cast<const float4*>(hrow + ks * 32 + 4);
        float fv[8] = {f0.x, f0.y, f0.z, f0.w, f1.x, f1.y, f1.z, f1.w};
#pragma unroll
        for (int q = 0; q < 8; ++q) {
            unsigned short h, lo;
            split_bf16(fv[q], h, lo);
            ahi[ks][q] = (short)h;
            alo[ks][q] = (short)lo;
        }
    }

    f32x4 acc[3];
#pragma unroll
    for (int nt = 0; nt < 3; ++nt) acc[nt] = {0.f, 0.f, 0.f, 0.f};

#pragma unroll
    for (int ks = 0; ks < 7; ++ks) {
#pragma unroll
        for (int nt = 0; nt < 3; ++nt) {
            size_t boff = (size_t)(nt * 16 + lr) * KPAD2 + ks * 32 + lg * 8;
            bf16x8 bhi = *reinterpret_cast<const bf16x8*>(w2hi + boff);
            bf16x8 blo = *reinterpret_cast<const bf16x8*>(w2lo + boff);
            acc[nt] = __builtin_amdgcn_mfma_f32_16x16x32_bf16(ahi[ks], bhi, acc[nt], 0, 0, 0);
            acc[nt] = __builtin_amdgcn_mfma_f32_16x16x32_bf16(alo[ks], bhi, acc[nt], 0, 0, 0);
            acc[nt] = __builtin_amdgcn_mfma_f32_16x16x32_bf16(ahi[ks], blo, acc[nt], 0, 0, 0);
        }
    }

    float ps[4] = {0.f, 0.f, 0.f, 0.f}, pd[4] = {0.f, 0.f, 0.f, 0.f};
#pragma unroll
    for (int nt = 0; nt < 3; ++nt) {
        int col = nt * 16 + lr;
        int cc = col < FOUT ? col : 0;
        float wsv = wsrc[cc]; wsv = col < FOUT ? wsv : 0.f;
        float wdv = wdst[cc]; wdv = col < FOUT ? wdv : 0.f;
#pragma unroll
        for (int r = 0; r < 4; ++r) { ps[r] += acc[nt][r] * wsv; pd[r] += acc[nt][r] * wdv; }
    }
#pragma unroll
    for (int r = 0; r < 4; ++r) {
#pragma unroll
        for (int off = 1; off < 16; off <<= 1) {
            ps[r] += __shfl_xor(ps[r], off);
            pd[r] += __shfl_xor(pd[r], off);
        }
        int row = row0 + lg * 4 + r;
        if (lr == 0 && row < M) { as2[row] = ps[r]; ad2[row] = pd[r]; }
    }

#pragma unroll
    for (int nt = 0; nt < 3; ++nt) {
        int col = nt * 16 + lr;
        if (col < FOUT) {
#pragma unroll
            for (int r = 0; r < 4; ++r) {
                int row = row0 + lg * 4 + r;
                if (row < M) Hb[(size_t)row * FOUT + col] = f2b(acc[nt][r]);
            }
        }
    }
}

// ---------------- CSR build ----------------
__global__ void hist_kernel(const int* __restrict__ dst, int* __restrict__ deg, int e) {
    int i = blockIdx.x * 256 + threadIdx.x;
    if (i < e) atomicAdd(&deg[dst[i]], 1);
}

__global__ __launch_bounds__(1024) void blockscan_kernel(const int* __restrict__ deg,
                                                         int* __restrict__ incl,
                                                         int* __restrict__ bsum, int n) {
    __shared__ int wtot[16];
    const int tid = threadIdx.x, lane = tid & 63, wid = tid >> 6;
    int i = blockIdx.x * 1024 + tid;
    int v = (i < n) ? deg[i] : 0;
    int x = v;
#pragma unroll
    for (int off = 1; off < 64; off <<= 1) {
        int up = __shfl_up(x, off);
        if (lane >= off) x += up;
    }
    if (lane == 63) wtot[wid] = x;
    __syncthreads();
    if (wid == 0) {
        int wv = (lane < 16) ? wtot[lane] : 0;
#pragma unroll
        for (int off = 1; off < 16; off <<= 1) {
            int up = __shfl_up(wv, off);
            if (lane >= off) wv += up;
        }
        if (lane < 16) wtot[lane] = wv;
    }
    __syncthreads();
    int xi = x + (wid ? wtot[wid - 1] : 0);
    if (i < n) incl[i] = xi;
    if (tid == 1023) bsum[blockIdx.x] = xi;
}

__global__ void sumscan_kernel(const int* __restrict__ bsum, int* __restrict__ boffs, int nb) {
    int lane = threadIdx.x;
    int v = (lane < nb) ? bsum[lane] : 0;
    int x = v;
#pragma unroll
    for (int off = 1; off < 64; off <<= 1) {
        int up = __shfl_up(x, off);
        if (lane >= off) x += up;
    }
    if (lane < nb) boffs[lane] = x - v;   // exclusive
}

__global__ void applyscan_kernel(const int* __restrict__ incl, const int* __restrict__ boffs,
                                 const int* __restrict__ deg, int* __restrict__ rowptr,
                                 int* __restrict__ cursor, int n) {
    int i = blockIdx.x * 256 + threadIdx.x;
    if (i < n) {
        int val = incl[i] + boffs[i >> 10];
        rowptr[i + 1] = val;
        cursor[i] = val - deg[i];
    }
    if (i == 0) rowptr[0] = 0;
}

__global__ void scatter_kernel(const int* __restrict__ src, const int* __restrict__ dst,
                               int* __restrict__ cursor, int* __restrict__ csrc, int e) {
    int i = blockIdx.x * 256 + threadIdx.x;
    if (i < e) {
        int d = dst[i];
        int pos = atomicAdd(&cursor[d], 1);
        csrc[pos] = src[i];
    }
}

// canonicalize per-node segment order (atomic scatter is nondeterministic):
// wave per node, 64-lane odd-even transposition sort. deg<=64 always holds here
// (Poisson mean 17); if it didn't, segment is left unsorted (still correct).
__global__ __launch_bounds__(256) void sort_segments(const int* __restrict__ rowptr,
                                                     int* __restrict__ csrc, int n) {
    int node = blockIdx.x * 4 + (threadIdx.x >> 6);
    if (node >= n) return;
    const int lane = threadIdx.x & 63;
    const int beg = rowptr[node], deg = rowptr[node + 1] - beg;
    if (deg > 64 || deg <= 1) return;
    int v = lane < deg ? csrc[beg + lane] : 0x7fffffff;
#pragma unroll 2
    for (int ph = 0; ph < 64; ++ph) {
        int partner;
        bool active;
        if ((ph & 1) == 0) { partner = lane ^ 1; active = true; }
        else {
            active = (lane > 0 && lane < 63);
            partner = active ? ((lane & 1) ? lane + 1 : lane - 1) : lane;
        }
        int pv = __shfl(v, partner);
        if (active) v = (lane < partner) ? min(v, pv) : max(v, pv);
    }
    if (lane < deg) csrc[beg + lane] = v;
}

// ------- layer-1 aggregation: wave/node, single pass; emits fp32 hcat padded to 224 -------
#define SEL4(hd, q0, q1, q2, q3) ((hd) == 0 ? (q0) : (hd) == 1 ? (q1) : (hd) == 2 ? (q2) : (q3))

__global__ __launch_bounds__(256) void gat_agg1(
    const unsigned short* __restrict__ Hb, const float* __restrict__ asrc,
    const float* __restrict__ adst, const int* __restrict__ rowptr,
    const int* __restrict__ csrc, const float* __restrict__ b1,
    float* __restrict__ hcat, int n) {
    int node = blockIdx.x * 4 + (threadIdx.x >> 6);
    if (node >= n) return;
    const int lane = threadIdx.x & 63;
    const int beg = rowptr[node], end = rowptr[node + 1];
    const float4 ad = reinterpret_cast<const float4*>(adst)[node];
    const bool act = lane < C1CH;
    const int ch0 = lane * 4;
    const int hd0 = ch0 / C1CH, hd1 = (ch0 + 1) / C1CH, hd2 = (ch0 + 2) / C1CH, hd3 = (ch0 + 3) / C1CH;

    float s0 = 0.f, s1 = 0.f, s2 = 0.f, s3 = 0.f;
    float a0 = 0.f, a1 = 0.f, a2 = 0.f, a3 = 0.f;
    const float4* as4 = reinterpret_cast<const float4*>(asrc);

    int j = beg;
    for (; j + 2 <= end; j += 2) {
        int sA = csrc[j], sB = csrc[j + 1];
        float4 avA = as4[sA], avB = as4[sB];
        ushort4 hA, hB;
        if (act) {
            hA = *reinterpret_cast<const ushort4*>(Hb + (size_t)sA * HID + ch0);
            hB = *reinterpret_cast<const ushort4*>(Hb + (size_t)sB * HID + ch0);
        }
        float pA0 = __expf(lrelu(avA.x + ad.x)), pA1 = __expf(lrelu(avA.y + ad.y));
        float pA2 = __expf(lrelu(avA.z + ad.z)), pA3 = __expf(lrelu(avA.w + ad.w));
        float pB0 = __expf(lrelu(avB.x + ad.x)), pB1 = __expf(lrelu(avB.y + ad.y));
        float pB2 = __expf(lrelu(avB.z + ad.z)), pB3 = __expf(lrelu(avB.w + ad.w));
        s0 += pA0 + pB0; s1 += pA1 + pB1; s2 += pA2 + pB2; s3 += pA3 + pB3;
        if (act) {
            a0 += SEL4(hd0, pA0, pA1, pA2, pA3) * b2f(hA.x) + SEL4(hd0, pB0, pB1, pB2, pB3) * b2f(hB.x);
            a1 += SEL4(hd1, pA0, pA1, pA2, pA3) * b2f(hA.y) + SEL4(hd1, pB0, pB1, pB2, pB3) * b2f(hB.y);
            a2 += SEL4(hd2, pA0, pA1, pA2, pA3) * b2f(hA.z) + SEL4(hd2, pB0, pB1, pB2, pB3) * b2f(hB.z);
            a3 += SEL4(hd3, pA0, pA1, pA2, pA3) * b2f(hA.w) + SEL4(hd3, pB0, pB1, pB2, pB3) * b2f(hB.w);
        }
    }
    if (j < end) {
        int sA = csrc[j];
        float4 avA = as4[sA];
        float pA0 = __expf(lrelu(avA.x + ad.x)), pA1 = __expf(lrelu(avA.y + ad.y));
        float pA2 = __expf(lrelu(avA.z + ad.z)), pA3 = __expf(lrelu(avA.w + ad.w));
        s0 += pA0; s1 += pA1; s2 += pA2; s3 += pA3;
        if (act) {
            ushort4 hA = *reinterpret_cast<const ushort4*>(Hb + (size_t)sA * HID + ch0);
            a0 += SEL4(hd0, pA0, pA1, pA2, pA3) * b2f(hA.x);
            a1 += SEL4(hd1, pA0, pA1, pA2, pA3) * b2f(hA.y);
            a2 += SEL4(hd2, pA0, pA1, pA2, pA3) * b2f(hA.z);
            a3 += SEL4(hd3, pA0, pA1, pA2, pA3) * b2f(hA.w);
        }
    }
    if (act) {
        float4 bv = reinterpret_cast<const float4*>(b1)[lane];
        float q0 = SEL4(hd0, s0, s1, s2, s3), q1 = SEL4(hd1, s0, s1, s2, s3);
        float q2 = SEL4(hd2, s0, s1, s2, s3), q3 = SEL4(hd3, s0, s1, s2, s3);
        float v0 = a0 / (q0 + 1e-16f) + bv.x;
        float v1 = a1 / (q1 + 1e-16f) + bv.y;
        float v2 = a2 / (q2 + 1e-16f) + bv.z;
        float v3 = a3 / (q3 + 1e-16f) + bv.w;
        v0 = v0 > 0.f ? v0 : __expf(v0) - 1.f;
        v1 = v1 > 0.f ? v1 : __expf(v1) - 1.f;
        v2 = v2 > 0.f ? v2 : __expf(v2) - 1.f;
        v3 = v3 > 0.f ? v3 : __expf(v3) - 1.f;
        reinterpret_cast<float4*>(hcat + (size_t)node * KPAD2)[lane] = make_float4(v0, v1, v2, v3);
    } else if (lane < 56) {  // zero the K-pad cols 200..223 (6 lanes x 4)
        reinterpret_cast<float4*>(hcat + (size_t)node * KPAD2)[lane] = make_float4(0.f, 0.f, 0.f, 0.f);
    }
}

// ------- layer-2 aggregation: wave/node, single pass, fused bias + log_softmax -------
__global__ __launch_bounds__(256) void gat_agg2(
    const unsigned short* __restrict__ Hb, const float* __restrict__ asrc,
    const float* __restrict__ adst, const int* __restrict__ rowptr,
    const int* __restrict__ csrc, const float* __restrict__ b2,
    float* __restrict__ outp, int n) {
    int node = blockIdx.x * 4 + (threadIdx.x >> 6);
    if (node >= n) return;
    const int lane = threadIdx.x & 63;
    const int beg = rowptr[node], end = rowptr[node + 1];
    const float ad = adst[node];
    const bool act = lane < FOUT;

    float ssum = 0.f, acc = 0.f;
    int j = beg;
    for (; j + 2 <= end; j += 2) {
        int sA = csrc[j], sB = csrc[j + 1];
        float eA = asrc[sA], eB = asrc[sB];
        unsigned short hA = 0, hB = 0;
        if (act) {
            hA = Hb[(size_t)sA * FOUT + lane];
            hB = Hb[(size_t)sB * FOUT + lane];
        }
        float pA = __expf(lrelu(eA + ad));
        float pB = __expf(lrelu(eB + ad));
        ssum += pA + pB;
        if (act) acc += pA * b2f(hA) + pB * b2f(hB);
    }
    if (j < end) {
        int sA = csrc[j];
        float pA = __expf(lrelu(asrc[sA] + ad));
        ssum += pA;
        if (act) acc += pA * b2f(Hb[(size_t)sA * FOUT + lane]);
    }
    float val = act ? (acc / (ssum + 1e-16f) + b2[lane]) : -1e30f;
    float mx = val;
#pragma unroll
    for (int off = 32; off >= 1; off >>= 1) mx = fmaxf(mx, __shfl_xor(mx, off));
    float ex = act ? __expf(val - mx) : 0.f;
    float z = ex;
#pragma unroll
    for (int off = 32; off >= 1; off >>= 1) z += __shfl_xor(z, off);
    if (act) outp[(size_t)node * FOUT + lane] = val - mx - __logf(z);
}

extern "C" void kernel_launch(void* const* d_in, const int* in_sizes, int n_in,
                              void* d_out, int out_size, void* d_ws, size_t ws_size,
                              hipStream_t stream) {
    const float* x        = (const float*)d_in[0];
    const int*   esrc     = (const int*)d_in[1];
    const int*   edst     = (const int*)d_in[2];
    const float* W1       = (const float*)d_in[3];
    const float* att_src1 = (const float*)d_in[4];
    const float* att_dst1 = (const float*)d_in[5];
    const float* b1       = (const float*)d_in[6];
    const float* W2       = (const float*)d_in[7];
    const float* att_src2 = (const float*)d_in[8];
    const float* att_dst2 = (const float*)d_in[9];
    const float* b2       = (const float*)d_in[10];
    float* out = (float*)d_out;

    const int n = NODES;
    const int e = in_sizes[1];
    const int nb = (n + 1023) / 1024;

    char* p = (char*)d_ws;
    auto alloc = [&](size_t bytes) -> char* {
        char* q = p;
        p += (bytes + 255) & ~(size_t)255;
        return q;
    };
    unsigned short* w1hi  = (unsigned short*)alloc((size_t)NPAD1 * FIN * 2);
    unsigned short* w1lo  = (unsigned short*)alloc((size_t)NPAD1 * FIN * 2);
    unsigned short* w2hi  = (unsigned short*)alloc((size_t)NPAD2 * KPAD2 * 2);
    unsigned short* w2lo  = (unsigned short*)alloc((size_t)NPAD2 * KPAD2 * 2);
    unsigned short* h1b   = (unsigned short*)alloc((size_t)n * HID * 2);
    float*          hcat  = (float*)alloc((size_t)n * KPAD2 * 4);
    unsigned short* h2b   = (unsigned short*)alloc((size_t)n * FOUT * 2);
    float* as1    = (float*)alloc((size_t)n * NH1 * 4);
    float* ad1    = (float*)alloc((size_t)n * NH1 * 4);
    float* as2    = (float*)alloc((size_t)n * 4);
    float* ad2    = (float*)alloc((size_t)n * 4);
    int*   deg    = (int*)alloc((size_t)n * 4);
    int*   incl   = (int*)alloc((size_t)n * 4);
    int*   rowptr = (int*)alloc((size_t)(n + 1) * 4);
    int*   cursor = (int*)alloc((size_t)n * 4);
    int*   csrc   = (int*)alloc((size_t)e * 4);
    int*   bsum   = (int*)alloc((size_t)nb * 4);
    int*   boffs  = (int*)alloc((size_t)nb * 4);
    if ((size_t)(p - (char*)d_ws) > ws_size) {
        fprintf(stderr, "kernel_launch: ws too small (%zu needed, %zu given)\n",
                (size_t)(p - (char*)d_ws), ws_size);
        return;
    }

    // CSR build + canonical segment order (deterministic output every call)
    hipMemsetAsync(deg, 0, (size_t)n * 4, stream);
    hist_kernel<<<(e + 255) / 256, 256, 0, stream>>>(edst, deg, e);
    blockscan_kernel<<<nb, 1024, 0, stream>>>(deg, incl, bsum, n);
    sumscan_kernel<<<1, 64, 0, stream>>>(bsum, boffs, nb);
    applyscan_kernel<<<(n + 255) / 256, 256, 0, stream>>>(incl, boffs, deg, rowptr, cursor, n);
    scatter_kernel<<<(e + 255) / 256, 256, 0, stream>>>(esrc, edst, cursor, csrc, e);
    sort_segments<<<(n + 3) / 4, 256, 0, stream>>>(rowptr, csrc, n);

    // weight prep (hi/lo split)
    prep_w1<<<(NPAD1 * FIN + 255) / 256, 256, 0, stream>>>(W1, w1hi, w1lo);
    prep_w2<<<(NPAD2 * KPAD2 + 255) / 256, 256, 0, stream>>>(W2, w2hi, w2lo);

    // layer 1
    gemm1_mfma<<<(n + 63) / 64, 256, 0, stream>>>(x, w1hi, w1lo, att_src1, att_dst1, h1b, as1, ad1, n);
    gat_agg1<<<(n + 3) / 4, 256, 0, stream>>>(h1b, as1, ad1, rowptr, csrc, b1, hcat, n);

    // layer 2
    gemm2_mfma<<<(n + 63) / 64, 256, 0, stream>>>(hcat, w2hi, w2lo, att_src2, att_dst2, h2b, as2, ad2, n);
    gat_agg2<<<(n + 3) / 4, 256, 0, stream>>>(h2b, as2, ad2, rowptr, csrc, b2, out, n);
}

// Round 6
// 328.027 us; speedup vs baseline: 2.0530x; 1.1629x over previous
//
#include <hip/hip_runtime.h>
#include <cstdint>
#include <cstdio>

#define NODES 50000
#define FIN   128
#define NH1   4
#define C1CH  50
#define HID   200   // NH1*C1CH
#define KPAD2 224   // HID padded to multiple of 32 for MFMA K-steps
#define FOUT  40
#define NPAD1 208   // HID padded to multiple of 16
#define NPAD2 48    // FOUT padded to multiple of 16

typedef __attribute__((ext_vector_type(8))) short bf16x8;
typedef __attribute__((ext_vector_type(4))) float f32x4;

// lrelu(x) = max(x, 0.2x): 2 VALU instrs, no cndmask
__device__ __forceinline__ float lrelu(float x) { return fmaxf(x, 0.2f * x); }
__device__ __forceinline__ float b2f(unsigned short u) {
    return __uint_as_float(((unsigned int)u) << 16);
}
__device__ __forceinline__ unsigned short f2b(float f) {
    unsigned int x = __float_as_uint(f);
    return (unsigned short)((x + 0x7fffu + ((x >> 16) & 1u)) >> 16);  // RNE
}
// split v into hi (bf16) + lo (bf16 of residual); hi+lo carries ~17 mantissa bits
__device__ __forceinline__ void split_bf16(float v, unsigned short& hi, unsigned short& lo) {
    hi = f2b(v);
    lo = f2b(v - b2f(hi));
}

#define SEL4(hd, q0, q1, q2, q3) ((hd) == 0 ? (q0) : (hd) == 1 ? (q1) : (hd) == 2 ? (q2) : (q3))

// ---------------- weight prep: transpose + hi/lo split ----------------
// W1 [128][200] fp32 -> W1^T hi/lo bf16 [208][128] (rows 200..207 zero)
__global__ void prep_w1(const float* __restrict__ W1, unsigned short* __restrict__ hi,
                        unsigned short* __restrict__ lo) {
    int i = blockIdx.x * 256 + threadIdx.x;
    if (i >= NPAD1 * FIN) return;
    int n = i >> 7, k = i & 127;
    float v = (n < HID) ? W1[(size_t)k * HID + n] : 0.f;
    unsigned short h, l;
    split_bf16(v, h, l);
    hi[i] = h; lo[i] = l;
}

// W2 [200][40] fp32 -> W2^T bf16 hi/lo [48][224] (zero padded both dims)
__global__ void prep_w2(const float* __restrict__ W2, unsigned short* __restrict__ hi,
                        unsigned short* __restrict__ lo) {
    int i = blockIdx.x * 256 + threadIdx.x;
    if (i >= NPAD2 * KPAD2) return;
    int n = i / KPAD2, k = i % KPAD2;
    float v = (n < FOUT && k < HID) ? W2[(size_t)k * FOUT + n] : 0.f;
    unsigned short h, l;
    split_bf16(v, h, l);
    hi[i] = h; lo[i] = l;
}

// ---------------- GEMM1 (split-bf16 MFMA, no LDS): h1 = x@W1, fused att1 ----------------
__global__ __launch_bounds__(256) void gemm1_mfma(
    const float* __restrict__ x, const unsigned short* __restrict__ w1hi,
    const unsigned short* __restrict__ w1lo,
    const float* __restrict__ wsrc, const float* __restrict__ wdst,
    unsigned short* __restrict__ Hb, float* __restrict__ as1, float* __restrict__ ad1, int M) {
    const int wid = threadIdx.x >> 6;
    const int l = threadIdx.x & 63, lr = l & 15, lg = l >> 4;
    const int row0 = blockIdx.x * 64 + wid * 16;

    int arow = row0 + lr; arow = arow < M ? arow : M - 1;
    const float* xrow = x + (size_t)arow * FIN + lg * 8;
    bf16x8 ahi[4], alo[4];
#pragma unroll
    for (int ks = 0; ks < 4; ++ks) {
        float4 f0 = *reinterpret_cast<const float4*>(xrow + ks * 32);
        float4 f1 = *reinterpret_cast<const float4*>(xrow + ks * 32 + 4);
        float fv[8] = {f0.x, f0.y, f0.z, f0.w, f1.x, f1.y, f1.z, f1.w};
#pragma unroll
        for (int q = 0; q < 8; ++q) {
            unsigned short h, lo;
            split_bf16(fv[q], h, lo);
            ahi[ks][q] = (short)h;
            alo[ks][q] = (short)lo;
        }
    }

    f32x4 acc[13];
#pragma unroll
    for (int nt = 0; nt < 13; ++nt) acc[nt] = {0.f, 0.f, 0.f, 0.f};

#pragma unroll
    for (int ks = 0; ks < 4; ++ks) {
#pragma unroll
        for (int nt = 0; nt < 13; ++nt) {
            size_t boff = (size_t)(nt * 16 + lr) * FIN + ks * 32 + lg * 8;
            bf16x8 bhi = *reinterpret_cast<const bf16x8*>(w1hi + boff);
            bf16x8 blo = *reinterpret_cast<const bf16x8*>(w1lo + boff);
            acc[nt] = __builtin_amdgcn_mfma_f32_16x16x32_bf16(ahi[ks], bhi, acc[nt], 0, 0, 0);
            acc[nt] = __builtin_amdgcn_mfma_f32_16x16x32_bf16(alo[ks], bhi, acc[nt], 0, 0, 0);
            acc[nt] = __builtin_amdgcn_mfma_f32_16x16x32_bf16(ahi[ks], blo, acc[nt], 0, 0, 0);
        }
    }

    // fused att1: per-lane head-segmented partial dot, 16-lane reduce
    float phs[4][4], phd[4][4];   // [reg][head]
#pragma unroll
    for (int r = 0; r < 4; ++r)
#pragma unroll
        for (int h = 0; h < 4; ++h) { phs[r][h] = 0.f; phd[r][h] = 0.f; }

#pragma unroll
    for (int nt = 0; nt < 13; ++nt) {
        int col = nt * 16 + lr;
        int cc = col < HID ? col : 0;
        float wsv = wsrc[cc]; wsv = col < HID ? wsv : 0.f;
        float wdv = wdst[cc]; wdv = col < HID ? wdv : 0.f;
        const int h_lo = (nt * 16) / C1CH;                 // compile-time after unroll
        const int splitc = (h_lo + 1) * C1CH - nt * 16;    // lanes lr<splitc -> h_lo
#pragma unroll
        for (int r = 0; r < 4; ++r) {
            float ps = acc[nt][r] * wsv, pd = acc[nt][r] * wdv;
            if (splitc >= 16) { phs[r][h_lo] += ps; phd[r][h_lo] += pd; }
            else if (h_lo < 3) {
                if (lr < splitc) { phs[r][h_lo] += ps; phd[r][h_lo] += pd; }
                else             { phs[r][h_lo + 1] += ps; phd[r][h_lo + 1] += pd; }
            } else { phs[r][3] += ps; phd[r][3] += pd; }   // nt=12 tail (cols>=200 are zero)
        }
    }

#pragma unroll
    for (int r = 0; r < 4; ++r) {
#pragma unroll
        for (int h = 0; h < 4; ++h) {
#pragma unroll
            for (int off = 1; off < 16; off <<= 1) {
                phs[r][h] += __shfl_xor(phs[r][h], off);
                phd[r][h] += __shfl_xor(phd[r][h], off);
            }
        }
        int row = row0 + lg * 4 + r;
        if (lr == 0 && row < M) {
            reinterpret_cast<float4*>(as1)[row] = make_float4(phs[r][0], phs[r][1], phs[r][2], phs[r][3]);
            reinterpret_cast<float4*>(ad1)[row] = make_float4(phd[r][0], phd[r][1], phd[r][2], phd[r][3]);
        }
    }

    // bf16 H store (gather operand for agg1)
#pragma unroll
    for (int nt = 0; nt < 13; ++nt) {
        int col = nt * 16 + lr;
        if (col < HID) {
#pragma unroll
            for (int r = 0; r < 4; ++r) {
                int row = row0 + lg * 4 + r;
                if (row < M) Hb[(size_t)row * HID + col] = f2b(acc[nt][r]);
            }
        }
    }
}

// ---------------- GEMM2 (split-bf16 MFMA, no LDS): h2 = hcat@W2, fused att2 ----------------
__global__ __launch_bounds__(256) void gemm2_mfma(
    const float* __restrict__ hcat, const unsigned short* __restrict__ w2hi,
    const unsigned short* __restrict__ w2lo,
    const float* __restrict__ wsrc, const float* __restrict__ wdst,
    unsigned short* __restrict__ Hb, float* __restrict__ as2, float* __restrict__ ad2, int M) {
    const int wid = threadIdx.x >> 6;
    const int l = threadIdx.x & 63, lr = l & 15, lg = l >> 4;
    const int row0 = blockIdx.x * 64 + wid * 16;

    int arow = row0 + lr; arow = arow < M ? arow : M - 1;
    const float* hrow = hcat + (size_t)arow * KPAD2 + lg * 8;
    bf16x8 ahi[7], alo[7];
#pragma unroll
    for (int ks = 0; ks < 7; ++ks) {
        float4 f0 = *reinterpret_cast<const float4*>(hrow + ks * 32);
        float4 f1 = *reinterpret_cast<const float4*>(hrow + ks * 32 + 4);
        float fv[8] = {f0.x, f0.y, f0.z, f0.w, f1.x, f1.y, f1.z, f1.w};
#pragma unroll
        for (int q = 0; q < 8; ++q) {
            unsigned short h, lo;
            split_bf16(fv[q], h, lo);
            ahi[ks][q] = (short)h;
            alo[ks][q] = (short)lo;
        }
    }

    f32x4 acc[3];
#pragma unroll
    for (int nt = 0; nt < 3; ++nt) acc[nt] = {0.f, 0.f, 0.f, 0.f};

#pragma unroll
    for (int ks = 0; ks < 7; ++ks) {
#pragma unroll
        for (int nt = 0; nt < 3; ++nt) {
            size_t boff = (size_t)(nt * 16 + lr) * KPAD2 + ks * 32 + lg * 8;
            bf16x8 bhi = *reinterpret_cast<const bf16x8*>(w2hi + boff);
            bf16x8 blo = *reinterpret_cast<const bf16x8*>(w2lo + boff);
            acc[nt] = __builtin_amdgcn_mfma_f32_16x16x32_bf16(ahi[ks], bhi, acc[nt], 0, 0, 0);
            acc[nt] = __builtin_amdgcn_mfma_f32_16x16x32_bf16(alo[ks], bhi, acc[nt], 0, 0, 0);
            acc[nt] = __builtin_amdgcn_mfma_f32_16x16x32_bf16(ahi[ks], blo, acc[nt], 0, 0, 0);
        }
    }

    float ps[4] = {0.f, 0.f, 0.f, 0.f}, pd[4] = {0.f, 0.f, 0.f, 0.f};
#pragma unroll
    for (int nt = 0; nt < 3; ++nt) {
        int col = nt * 16 + lr;
        int cc = col < FOUT ? col : 0;
        float wsv = wsrc[cc]; wsv = col < FOUT ? wsv : 0.f;
        float wdv = wdst[cc]; wdv = col < FOUT ? wdv : 0.f;
#pragma unroll
        for (int r = 0; r < 4; ++r) { ps[r] += acc[nt][r] * wsv; pd[r] += acc[nt][r] * wdv; }
    }
#pragma unroll
    for (int r = 0; r < 4; ++r) {
#pragma unroll
        for (int off = 1; off < 16; off <<= 1) {
            ps[r] += __shfl_xor(ps[r], off);
            pd[r] += __shfl_xor(pd[r], off);
        }
        int row = row0 + lg * 4 + r;
        if (lr == 0 && row < M) { as2[row] = ps[r]; ad2[row] = pd[r]; }
    }

#pragma unroll
    for (int nt = 0; nt < 3; ++nt) {
        int col = nt * 16 + lr;
        if (col < FOUT) {
#pragma unroll
            for (int r = 0; r < 4; ++r) {
                int row = row0 + lg * 4 + r;
                if (row < M) Hb[(size_t)row * FOUT + col] = f2b(acc[nt][r]);
            }
        }
    }
}

// ---------------- CSR build ----------------
__global__ void hist_kernel(const int* __restrict__ dst, int* __restrict__ deg, int e) {
    int i = blockIdx.x * 256 + threadIdx.x;
    if (i < e) atomicAdd(&deg[dst[i]], 1);
}

__global__ __launch_bounds__(1024) void blockscan_kernel(const int* __restrict__ deg,
                                                         int* __restrict__ incl,
                                                         int* __restrict__ bsum, int n) {
    __shared__ int wtot[16];
    const int tid = threadIdx.x, lane = tid & 63, wid = tid >> 6;
    int i = blockIdx.x * 1024 + tid;
    int v = (i < n) ? deg[i] : 0;
    int x = v;
#pragma unroll
    for (int off = 1; off < 64; off <<= 1) {
        int up = __shfl_up(x, off);
        if (lane >= off) x += up;
    }
    if (lane == 63) wtot[wid] = x;
    __syncthreads();
    if (wid == 0) {
        int wv = (lane < 16) ? wtot[lane] : 0;
#pragma unroll
        for (int off = 1; off < 16; off <<= 1) {
            int up = __shfl_up(wv, off);
            if (lane >= off) wv += up;
        }
        if (lane < 16) wtot[lane] = wv;
    }
    __syncthreads();
    int xi = x + (wid ? wtot[wid - 1] : 0);
    if (i < n) incl[i] = xi;
    if (tid == 1023) bsum[blockIdx.x] = xi;
}

__global__ void sumscan_kernel(const int* __restrict__ bsum, int* __restrict__ boffs, int nb) {
    int lane = threadIdx.x;
    int v = (lane < nb) ? bsum[lane] : 0;
    int x = v;
#pragma unroll
    for (int off = 1; off < 64; off <<= 1) {
        int up = __shfl_up(x, off);
        if (lane >= off) x += up;
    }
    if (lane < nb) boffs[lane] = x - v;   // exclusive
}

__global__ void applyscan_kernel(const int* __restrict__ incl, const int* __restrict__ boffs,
                                 const int* __restrict__ deg, int* __restrict__ rowptr,
                                 int* __restrict__ cursor, int n) {
    int i = blockIdx.x * 256 + threadIdx.x;
    if (i < n) {
        int val = incl[i] + boffs[i >> 10];
        rowptr[i + 1] = val;
        cursor[i] = val - deg[i];
    }
    if (i == 0) rowptr[0] = 0;
}

__global__ void scatter_kernel(const int* __restrict__ src, const int* __restrict__ dst,
                               int* __restrict__ cursor, int* __restrict__ csrc, int e) {
    int i = blockIdx.x * 256 + threadIdx.x;
    if (i < e) {
        int d = dst[i];
        int pos = atomicAdd(&cursor[d], 1);
        csrc[pos] = src[i];
    }
}

// canonicalize per-node segment order (atomic scatter is nondeterministic):
// wave per node, full 64-lane Batcher bitonic sort (21 fixed compare-exchange
// steps; sorts all 64 slots unconditionally, INT_MAX sentinels beyond deg).
// deg>64 never occurs (Poisson mean 17), but a serial fallback keeps the
// pipeline deterministic unconditionally.
__global__ __launch_bounds__(256) void sort_segments(const int* __restrict__ rowptr,
                                                     int* __restrict__ csrc, int n) {
    int node = blockIdx.x * 4 + (threadIdx.x >> 6);
    if (node >= n) return;
    const int lane = threadIdx.x & 63;
    const int beg = rowptr[node], deg = rowptr[node + 1] - beg;
    if (deg <= 1) return;
    if (deg > 64) {
        if (lane == 0) {   // unreachable in practice; determinism safety net
            for (int i = beg + 1; i < beg + deg; ++i) {
                int key = csrc[i]; int j2 = i - 1;
                while (j2 >= beg && csrc[j2] > key) { csrc[j2 + 1] = csrc[j2]; --j2; }
                csrc[j2 + 1] = key;
            }
        }
        return;
    }
    int v = lane < deg ? csrc[beg + lane] : 0x7fffffff;
#pragma unroll
    for (int k = 2; k <= 64; k <<= 1) {
#pragma unroll
        for (int j = k >> 1; j > 0; j >>= 1) {
            int pv = __shfl_xor(v, j);
            bool up = (lane & k) == 0;
            bool takeMin = ((lane & j) == 0) == up;
            int mn = min(v, pv), mx = max(v, pv);
            v = takeMin ? mn : mx;
        }
    }
    if (lane < deg) csrc[beg + lane] = v;
}

// ------- layer-1 aggregation: wave/node, single pass, per-lane 2-head score chains -------
// lane owns channels ch0..ch0+3 (ch0=lane*4); these span heads hd0..hd3 with hd3<=hd0+1.
// Only 2 exp chains per edge per lane; channels 1,2 select via precomputed cndmask.
__global__ __launch_bounds__(256) void gat_agg1(
    const unsigned short* __restrict__ Hb, const float* __restrict__ asrc,
    const float* __restrict__ adst, const int* __restrict__ rowptr,
    const int* __restrict__ csrc, const float* __restrict__ b1,
    float* __restrict__ hcat, int n) {
    int node = blockIdx.x * 4 + (threadIdx.x >> 6);
    if (node >= n) return;
    const int lane = threadIdx.x & 63;
    const int beg = rowptr[node], end = rowptr[node + 1];
    const bool act = lane < C1CH;
    const int ch0 = act ? lane * 4 : 0;          // clamped for safe addressing
    const int hd0 = ch0 / C1CH;
    const int hd3 = (ch0 + 3) / C1CH;            // <=3 when act; 0 otherwise
    const bool c1 = ((ch0 + 1) / C1CH) == hd0;
    const bool c2 = ((ch0 + 2) / C1CH) == hd0;
    const float4 adv = reinterpret_cast<const float4*>(adst)[node];
    const float ad0 = SEL4(hd0, adv.x, adv.y, adv.z, adv.w);
    const float ad3 = SEL4(hd3, adv.x, adv.y, adv.z, adv.w);

    float ssum0 = 0.f, ssum3 = 0.f;
    float a0 = 0.f, a1 = 0.f, a2 = 0.f, a3 = 0.f;

    int j = beg;
    for (; j + 2 <= end; j += 2) {
        int sA = csrc[j], sB = csrc[j + 1];
        float e0A = asrc[sA * 4 + hd0], e3A = asrc[sA * 4 + hd3];
        float e0B = asrc[sB * 4 + hd0], e3B = asrc[sB * 4 + hd3];
        ushort4 hA = *reinterpret_cast<const ushort4*>(Hb + (size_t)sA * HID + ch0);
        ushort4 hB = *reinterpret_cast<const ushort4*>(Hb + (size_t)sB * HID + ch0);
        float p0A = __expf(lrelu(e0A + ad0));
        float p3A = __expf(lrelu(e3A + ad3));
        float p0B = __expf(lrelu(e0B + ad0));
        float p3B = __expf(lrelu(e3B + ad3));
        ssum0 += p0A + p0B; ssum3 += p3A + p3B;
        float p1A = c1 ? p0A : p3A, p2A = c2 ? p0A : p3A;
        float p1B = c1 ? p0B : p3B, p2B = c2 ? p0B : p3B;
        a0 += p0A * b2f(hA.x) + p0B * b2f(hB.x);
        a1 += p1A * b2f(hA.y) + p1B * b2f(hB.y);
        a2 += p2A * b2f(hA.z) + p2B * b2f(hB.z);
        a3 += p3A * b2f(hA.w) + p3B * b2f(hB.w);
    }
    if (j < end) {
        int sA = csrc[j];
        float e0A = asrc[sA * 4 + hd0], e3A = asrc[sA * 4 + hd3];
        ushort4 hA = *reinterpret_cast<const ushort4*>(Hb + (size_t)sA * HID + ch0);
        float p0A = __expf(lrelu(e0A + ad0));
        float p3A = __expf(lrelu(e3A + ad3));
        ssum0 += p0A; ssum3 += p3A;
        float p1A = c1 ? p0A : p3A, p2A = c2 ? p0A : p3A;
        a0 += p0A * b2f(hA.x);
        a1 += p1A * b2f(hA.y);
        a2 += p2A * b2f(hA.z);
        a3 += p3A * b2f(hA.w);
    }
    if (act) {
        const float n0 = ssum0 + 1e-16f, n3 = ssum3 + 1e-16f;
        const float n1 = c1 ? n0 : n3, n2 = c2 ? n0 : n3;
        float4 bv = reinterpret_cast<const float4*>(b1)[lane];
        float v0 = a0 / n0 + bv.x;
        float v1 = a1 / n1 + bv.y;
        float v2 = a2 / n2 + bv.z;
        float v3 = a3 / n3 + bv.w;
        v0 = v0 > 0.f ? v0 : __expf(v0) - 1.f;
        v1 = v1 > 0.f ? v1 : __expf(v1) - 1.f;
        v2 = v2 > 0.f ? v2 : __expf(v2) - 1.f;
        v3 = v3 > 0.f ? v3 : __expf(v3) - 1.f;
        reinterpret_cast<float4*>(hcat + (size_t)node * KPAD2)[lane] = make_float4(v0, v1, v2, v3);
    } else if (lane < 56) {  // zero the K-pad cols 200..223 (6 lanes x 4)
        reinterpret_cast<float4*>(hcat + (size_t)node * KPAD2)[lane] = make_float4(0.f, 0.f, 0.f, 0.f);
    }
}

// ------- layer-2 aggregation: wave/node, single pass, fused bias + log_softmax -------
__global__ __launch_bounds__(256) void gat_agg2(
    const unsigned short* __restrict__ Hb, const float* __restrict__ asrc,
    const float* __restrict__ adst, const int* __restrict__ rowptr,
    const int* __restrict__ csrc, const float* __restrict__ b2,
    float* __restrict__ outp, int n) {
    int node = blockIdx.x * 4 + (threadIdx.x >> 6);
    if (node >= n) return;
    const int lane = threadIdx.x & 63;
    const int beg = rowptr[node], end = rowptr[node + 1];
    const float ad = adst[node];
    const bool act = lane < FOUT;
    const int lc = act ? lane : 0;   // clamped channel for safe loads

    float ssum = 0.f, acc = 0.f;
    int j = beg;
    for (; j + 2 <= end; j += 2) {
        int sA = csrc[j], sB = csrc[j + 1];
        float eA = asrc[sA], eB = asrc[sB];
        unsigned short hA = Hb[(size_t)sA * FOUT + lc];
        unsigned short hB = Hb[(size_t)sB * FOUT + lc];
        float pA = __expf(lrelu(eA + ad));
        float pB = __expf(lrelu(eB + ad));
        ssum += pA + pB;
        acc += pA * b2f(hA) + pB * b2f(hB);
    }
    if (j < end) {
        int sA = csrc[j];
        float pA = __expf(lrelu(asrc[sA] + ad));
        ssum += pA;
        acc += pA * b2f(Hb[(size_t)sA * FOUT + lc]);
    }
    float val = act ? (acc / (ssum + 1e-16f) + b2[lane]) : -1e30f;
    float mx = val;
#pragma unroll
    for (int off = 32; off >= 1; off >>= 1) mx = fmaxf(mx, __shfl_xor(mx, off));
    float ex = act ? __expf(val - mx) : 0.f;
    float z = ex;
#pragma unroll
    for (int off = 32; off >= 1; off >>= 1) z += __shfl_xor(z, off);
    if (act) outp[(size_t)node * FOUT + lane] = val - mx - __logf(z);
}

extern "C" void kernel_launch(void* const* d_in, const int* in_sizes, int n_in,
                              void* d_out, int out_size, void* d_ws, size_t ws_size,
                              hipStream_t stream) {
    const float* x        = (const float*)d_in[0];
    const int*   esrc     = (const int*)d_in[1];
    const int*   edst     = (const int*)d_in[2];
    const float* W1       = (const float*)d_in[3];
    const float* att_src1 = (const float*)d_in[4];
    const float* att_dst1 = (const float*)d_in[5];
    const float* b1       = (const float*)d_in[6];
    const float* W2       = (const float*)d_in[7];
    const float* att_src2 = (const float*)d_in[8];
    const float* att_dst2 = (const float*)d_in[9];
    const float* b2       = (const float*)d_in[10];
    float* out = (float*)d_out;

    const int n = NODES;
    const int e = in_sizes[1];
    const int nb = (n + 1023) / 1024;

    char* p = (char*)d_ws;
    auto alloc = [&](size_t bytes) -> char* {
        char* q = p;
        p += (bytes + 255) & ~(size_t)255;
        return q;
    };
    unsigned short* w1hi  = (unsigned short*)alloc((size_t)NPAD1 * FIN * 2);
    unsigned short* w1lo  = (unsigned short*)alloc((size_t)NPAD1 * FIN * 2);
    unsigned short* w2hi  = (unsigned short*)alloc((size_t)NPAD2 * KPAD2 * 2);
    unsigned short* w2lo  = (unsigned short*)alloc((size_t)NPAD2 * KPAD2 * 2);
    unsigned short* h1b   = (unsigned short*)alloc((size_t)n * HID * 2);
    float*          hcat  = (float*)alloc((size_t)n * KPAD2 * 4);
    unsigned short* h2b   = (unsigned short*)alloc((size_t)n * FOUT * 2);
    float* as1    = (float*)alloc((size_t)n * NH1 * 4);
    float* ad1    = (float*)alloc((size_t)n * NH1 * 4);
    float* as2    = (float*)alloc((size_t)n * 4);
    float* ad2    = (float*)alloc((size_t)n * 4);
    int*   deg    = (int*)alloc((size_t)n * 4);
    int*   incl   = (int*)alloc((size_t)n * 4);
    int*   rowptr = (int*)alloc((size_t)(n + 1) * 4);
    int*   cursor = (int*)alloc((size_t)n * 4);
    int*   csrc   = (int*)alloc((size_t)e * 4);
    int*   bsum   = (int*)alloc((size_t)nb * 4);
    int*   boffs  = (int*)alloc((size_t)nb * 4);
    if ((size_t)(p - (char*)d_ws) > ws_size) {
        fprintf(stderr, "kernel_launch: ws too small (%zu needed, %zu given)\n",
                (size_t)(p - (char*)d_ws), ws_size);
        return;
    }

    // CSR build + canonical segment order (deterministic output every call)
    hipMemsetAsync(deg, 0, (size_t)n * 4, stream);
    hist_kernel<<<(e + 255) / 256, 256, 0, stream>>>(edst, deg, e);
    blockscan_kernel<<<nb, 1024, 0, stream>>>(deg, incl, bsum, n);
    sumscan_kernel<<<1, 64, 0, stream>>>(bsum, boffs, nb);
    applyscan_kernel<<<(n + 255) / 256, 256, 0, stream>>>(incl, boffs, deg, rowptr, cursor, n);
    scatter_kernel<<<(e + 255) / 256, 256, 0, stream>>>(esrc, edst, cursor, csrc, e);
    sort_segments<<<(n + 3) / 4, 256, 0, stream>>>(rowptr, csrc, n);

    // weight prep (hi/lo split)
    prep_w1<<<(NPAD1 * FIN + 255) / 256, 256, 0, stream>>>(W1, w1hi, w1lo);
    prep_w2<<<(NPAD2 * KPAD2 + 255) / 256, 256, 0, stream>>>(W2, w2hi, w2lo);

    // layer 1
    gemm1_mfma<<<(n + 63) / 64, 256, 0, stream>>>(x, w1hi, w1lo, att_src1, att_dst1, h1b, as1, ad1, n);
    gat_agg1<<<(n + 3) / 4, 256, 0, stream>>>(h1b, as1, ad1, rowptr, csrc, b1, hcat, n);

    // layer 2
    gemm2_mfma<<<(n + 63) / 64, 256, 0, stream>>>(hcat, w2hi, w2lo, att_src2, att_dst2, h2b, as2, ad2, n);
    gat_agg2<<<(n + 3) / 4, 256, 0, stream>>>(h2b, as2, ad2, rowptr, csrc, b2, out, n);
}

// Round 7
// 306.705 us; speedup vs baseline: 2.1957x; 1.0695x over previous
//
#include <hip/hip_runtime.h>
#include <cstdint>
#include <cstdio>

#define NODES 50000
#define FIN   128
#define NH1   4
#define C1CH  50
#define HID   200   // NH1*C1CH
#define KPAD2 224   // HID padded to multiple of 32 for MFMA K-steps
#define FOUT  40
#define NPAD1 208   // HID padded to multiple of 16
#define NPAD2 48    // FOUT padded to multiple of 16

typedef __attribute__((ext_vector_type(8))) short bf16x8;
typedef __attribute__((ext_vector_type(4))) float f32x4;

// lrelu(x) = max(x, 0.2x): 2 VALU instrs, no cndmask
__device__ __forceinline__ float lrelu(float x) { return fmaxf(x, 0.2f * x); }
__device__ __forceinline__ float b2f(unsigned short u) {
    return __uint_as_float(((unsigned int)u) << 16);
}
__device__ __forceinline__ unsigned short f2b(float f) {
    unsigned int x = __float_as_uint(f);
    return (unsigned short)((x + 0x7fffu + ((x >> 16) & 1u)) >> 16);  // RNE
}
// split v into hi (bf16) + lo (bf16 of residual); hi+lo carries ~17 mantissa bits
__device__ __forceinline__ void split_bf16(float v, unsigned short& hi, unsigned short& lo) {
    hi = f2b(v);
    lo = f2b(v - b2f(hi));
}

#define SEL4(hd, q0, q1, q2, q3) ((hd) == 0 ? (q0) : (hd) == 1 ? (q1) : (hd) == 2 ? (q2) : (q3))

// ---------------- weight prep: transpose + hi/lo split ----------------
// W1 [128][200] fp32 -> W1^T hi/lo bf16 [208][128] (rows 200..207 zero)
__global__ void prep_w1(const float* __restrict__ W1, unsigned short* __restrict__ hi,
                        unsigned short* __restrict__ lo) {
    int i = blockIdx.x * 256 + threadIdx.x;
    if (i >= NPAD1 * FIN) return;
    int n = i >> 7, k = i & 127;
    float v = (n < HID) ? W1[(size_t)k * HID + n] : 0.f;
    unsigned short h, l;
    split_bf16(v, h, l);
    hi[i] = h; lo[i] = l;
}

// W2 [200][40] fp32 -> W2^T bf16 hi/lo [48][224] (zero padded both dims)
__global__ void prep_w2(const float* __restrict__ W2, unsigned short* __restrict__ hi,
                        unsigned short* __restrict__ lo) {
    int i = blockIdx.x * 256 + threadIdx.x;
    if (i >= NPAD2 * KPAD2) return;
    int n = i / KPAD2, k = i % KPAD2;
    float v = (n < FOUT && k < HID) ? W2[(size_t)k * FOUT + n] : 0.f;
    unsigned short h, l;
    split_bf16(v, h, l);
    hi[i] = h; lo[i] = l;
}

// ---------------- GEMM1 (split-bf16 MFMA, no LDS): h1 = x@W1, fused att1 ----------------
__global__ __launch_bounds__(256) void gemm1_mfma(
    const float* __restrict__ x, const unsigned short* __restrict__ w1hi,
    const unsigned short* __restrict__ w1lo,
    const float* __restrict__ wsrc, const float* __restrict__ wdst,
    unsigned short* __restrict__ Hb, float* __restrict__ as1, float* __restrict__ ad1, int M) {
    const int wid = threadIdx.x >> 6;
    const int l = threadIdx.x & 63, lr = l & 15, lg = l >> 4;
    const int row0 = blockIdx.x * 64 + wid * 16;

    int arow = row0 + lr; arow = arow < M ? arow : M - 1;
    const float* xrow = x + (size_t)arow * FIN + lg * 8;
    bf16x8 ahi[4], alo[4];
#pragma unroll
    for (int ks = 0; ks < 4; ++ks) {
        float4 f0 = *reinterpret_cast<const float4*>(xrow + ks * 32);
        float4 f1 = *reinterpret_cast<const float4*>(xrow + ks * 32 + 4);
        float fv[8] = {f0.x, f0.y, f0.z, f0.w, f1.x, f1.y, f1.z, f1.w};
#pragma unroll
        for (int q = 0; q < 8; ++q) {
            unsigned short h, lo;
            split_bf16(fv[q], h, lo);
            ahi[ks][q] = (short)h;
            alo[ks][q] = (short)lo;
        }
    }

    f32x4 acc[13];
#pragma unroll
    for (int nt = 0; nt < 13; ++nt) acc[nt] = {0.f, 0.f, 0.f, 0.f};

#pragma unroll
    for (int ks = 0; ks < 4; ++ks) {
#pragma unroll
        for (int nt = 0; nt < 13; ++nt) {
            size_t boff = (size_t)(nt * 16 + lr) * FIN + ks * 32 + lg * 8;
            bf16x8 bhi = *reinterpret_cast<const bf16x8*>(w1hi + boff);
            bf16x8 blo = *reinterpret_cast<const bf16x8*>(w1lo + boff);
            acc[nt] = __builtin_amdgcn_mfma_f32_16x16x32_bf16(ahi[ks], bhi, acc[nt], 0, 0, 0);
            acc[nt] = __builtin_amdgcn_mfma_f32_16x16x32_bf16(alo[ks], bhi, acc[nt], 0, 0, 0);
            acc[nt] = __builtin_amdgcn_mfma_f32_16x16x32_bf16(ahi[ks], blo, acc[nt], 0, 0, 0);
        }
    }

    // fused att1: per-lane head-segmented partial dot, 16-lane reduce
    float phs[4][4], phd[4][4];   // [reg][head]
#pragma unroll
    for (int r = 0; r < 4; ++r)
#pragma unroll
        for (int h = 0; h < 4; ++h) { phs[r][h] = 0.f; phd[r][h] = 0.f; }

#pragma unroll
    for (int nt = 0; nt < 13; ++nt) {
        int col = nt * 16 + lr;
        int cc = col < HID ? col : 0;
        float wsv = wsrc[cc]; wsv = col < HID ? wsv : 0.f;
        float wdv = wdst[cc]; wdv = col < HID ? wdv : 0.f;
        const int h_lo = (nt * 16) / C1CH;                 // compile-time after unroll
        const int splitc = (h_lo + 1) * C1CH - nt * 16;    // lanes lr<splitc -> h_lo
#pragma unroll
        for (int r = 0; r < 4; ++r) {
            float ps = acc[nt][r] * wsv, pd = acc[nt][r] * wdv;
            if (splitc >= 16) { phs[r][h_lo] += ps; phd[r][h_lo] += pd; }
            else if (h_lo < 3) {
                if (lr < splitc) { phs[r][h_lo] += ps; phd[r][h_lo] += pd; }
                else             { phs[r][h_lo + 1] += ps; phd[r][h_lo + 1] += pd; }
            } else { phs[r][3] += ps; phd[r][3] += pd; }   // nt=12 tail (cols>=200 are zero)
        }
    }

#pragma unroll
    for (int r = 0; r < 4; ++r) {
#pragma unroll
        for (int h = 0; h < 4; ++h) {
#pragma unroll
            for (int off = 1; off < 16; off <<= 1) {
                phs[r][h] += __shfl_xor(phs[r][h], off);
                phd[r][h] += __shfl_xor(phd[r][h], off);
            }
        }
        int row = row0 + lg * 4 + r;
        if (lr == 0 && row < M) {
            reinterpret_cast<float4*>(as1)[row] = make_float4(phs[r][0], phs[r][1], phs[r][2], phs[r][3]);
            reinterpret_cast<float4*>(ad1)[row] = make_float4(phd[r][0], phd[r][1], phd[r][2], phd[r][3]);
        }
    }

    // bf16 H store (gather operand for agg1)
#pragma unroll
    for (int nt = 0; nt < 13; ++nt) {
        int col = nt * 16 + lr;
        if (col < HID) {
#pragma unroll
            for (int r = 0; r < 4; ++r) {
                int row = row0 + lg * 4 + r;
                if (row < M) Hb[(size_t)row * HID + col] = f2b(acc[nt][r]);
            }
        }
    }
}

// ---------------- GEMM2 (split-bf16 MFMA, no LDS): h2 = hcat@W2, fused att2 ----------------
// A operand read directly as precomputed hi/lo bf16 pairs (no in-register split).
__global__ __launch_bounds__(256) void gemm2_mfma(
    const unsigned short* __restrict__ hcat_hi, const unsigned short* __restrict__ hcat_lo,
    const unsigned short* __restrict__ w2hi, const unsigned short* __restrict__ w2lo,
    const float* __restrict__ wsrc, const float* __restrict__ wdst,
    unsigned short* __restrict__ Hb, float* __restrict__ as2, float* __restrict__ ad2, int M) {
    const int wid = threadIdx.x >> 6;
    const int l = threadIdx.x & 63, lr = l & 15, lg = l >> 4;
    const int row0 = blockIdx.x * 64 + wid * 16;

    int arow = row0 + lr; arow = arow < M ? arow : M - 1;
    const unsigned short* hrh = hcat_hi + (size_t)arow * KPAD2 + lg * 8;
    const unsigned short* hrl = hcat_lo + (size_t)arow * KPAD2 + lg * 8;
    bf16x8 ahi[7], alo[7];
#pragma unroll
    for (int ks = 0; ks < 7; ++ks) {
        ahi[ks] = *reinterpret_cast<const bf16x8*>(hrh + ks * 32);
        alo[ks] = *reinterpret_cast<const bf16x8*>(hrl + ks * 32);
    }

    f32x4 acc[3];
#pragma unroll
    for (int nt = 0; nt < 3; ++nt) acc[nt] = {0.f, 0.f, 0.f, 0.f};

#pragma unroll
    for (int ks = 0; ks < 7; ++ks) {
#pragma unroll
        for (int nt = 0; nt < 3; ++nt) {
            size_t boff = (size_t)(nt * 16 + lr) * KPAD2 + ks * 32 + lg * 8;
            bf16x8 bhi = *reinterpret_cast<const bf16x8*>(w2hi + boff);
            bf16x8 blo = *reinterpret_cast<const bf16x8*>(w2lo + boff);
            acc[nt] = __builtin_amdgcn_mfma_f32_16x16x32_bf16(ahi[ks], bhi, acc[nt], 0, 0, 0);
            acc[nt] = __builtin_amdgcn_mfma_f32_16x16x32_bf16(alo[ks], bhi, acc[nt], 0, 0, 0);
            acc[nt] = __builtin_amdgcn_mfma_f32_16x16x32_bf16(ahi[ks], blo, acc[nt], 0, 0, 0);
        }
    }

    float ps[4] = {0.f, 0.f, 0.f, 0.f}, pd[4] = {0.f, 0.f, 0.f, 0.f};
#pragma unroll
    for (int nt = 0; nt < 3; ++nt) {
        int col = nt * 16 + lr;
        int cc = col < FOUT ? col : 0;
        float wsv = wsrc[cc]; wsv = col < FOUT ? wsv : 0.f;
        float wdv = wdst[cc]; wdv = col < FOUT ? wdv : 0.f;
#pragma unroll
        for (int r = 0; r < 4; ++r) { ps[r] += acc[nt][r] * wsv; pd[r] += acc[nt][r] * wdv; }
    }
#pragma unroll
    for (int r = 0; r < 4; ++r) {
#pragma unroll
        for (int off = 1; off < 16; off <<= 1) {
            ps[r] += __shfl_xor(ps[r], off);
            pd[r] += __shfl_xor(pd[r], off);
        }
        int row = row0 + lg * 4 + r;
        if (lr == 0 && row < M) { as2[row] = ps[r]; ad2[row] = pd[r]; }
    }

#pragma unroll
    for (int nt = 0; nt < 3; ++nt) {
        int col = nt * 16 + lr;
        if (col < FOUT) {
#pragma unroll
            for (int r = 0; r < 4; ++r) {
                int row = row0 + lg * 4 + r;
                if (row < M) Hb[(size_t)row * FOUT + col] = f2b(acc[nt][r]);
            }
        }
    }
}

// ---------------- CSR build ----------------
__global__ void hist_kernel(const int* __restrict__ dst, int* __restrict__ deg, int e) {
    int i = blockIdx.x * 256 + threadIdx.x;
    if (i < e) atomicAdd(&deg[dst[i]], 1);
}

__global__ __launch_bounds__(1024) void blockscan_kernel(const int* __restrict__ deg,
                                                         int* __restrict__ incl,
                                                         int* __restrict__ bsum, int n) {
    __shared__ int wtot[16];
    const int tid = threadIdx.x, lane = tid & 63, wid = tid >> 6;
    int i = blockIdx.x * 1024 + tid;
    int v = (i < n) ? deg[i] : 0;
    int x = v;
#pragma unroll
    for (int off = 1; off < 64; off <<= 1) {
        int up = __shfl_up(x, off);
        if (lane >= off) x += up;
    }
    if (lane == 63) wtot[wid] = x;
    __syncthreads();
    if (wid == 0) {
        int wv = (lane < 16) ? wtot[lane] : 0;
#pragma unroll
        for (int off = 1; off < 16; off <<= 1) {
            int up = __shfl_up(wv, off);
            if (lane >= off) wv += up;
        }
        if (lane < 16) wtot[lane] = wv;
    }
    __syncthreads();
    int xi = x + (wid ? wtot[wid - 1] : 0);
    if (i < n) incl[i] = xi;
    if (tid == 1023) bsum[blockIdx.x] = xi;
}

__global__ void sumscan_kernel(const int* __restrict__ bsum, int* __restrict__ boffs, int nb) {
    int lane = threadIdx.x;
    int v = (lane < nb) ? bsum[lane] : 0;
    int x = v;
#pragma unroll
    for (int off = 1; off < 64; off <<= 1) {
        int up = __shfl_up(x, off);
        if (lane >= off) x += up;
    }
    if (lane < nb) boffs[lane] = x - v;   // exclusive
}

__global__ void applyscan_kernel(const int* __restrict__ incl, const int* __restrict__ boffs,
                                 const int* __restrict__ deg, int* __restrict__ rowptr,
                                 int* __restrict__ cursor, int n) {
    int i = blockIdx.x * 256 + threadIdx.x;
    if (i < n) {
        int val = incl[i] + boffs[i >> 10];
        rowptr[i + 1] = val;
        cursor[i] = val - deg[i];
    }
    if (i == 0) rowptr[0] = 0;
}

__global__ void scatter_kernel(const int* __restrict__ src, const int* __restrict__ dst,
                               int* __restrict__ cursor, int* __restrict__ csrc, int e) {
    int i = blockIdx.x * 256 + threadIdx.x;
    if (i < e) {
        int d = dst[i];
        int pos = atomicAdd(&cursor[d], 1);
        csrc[pos] = src[i];
    }
}

// canonicalize per-node segment order (atomic scatter is nondeterministic):
// wave per node, full 64-lane Batcher bitonic sort (21 fixed compare-exchange
// steps; sorts all 64 slots unconditionally, INT_MAX sentinels beyond deg).
__global__ __launch_bounds__(256) void sort_segments(const int* __restrict__ rowptr,
                                                     int* __restrict__ csrc, int n) {
    int node = blockIdx.x * 4 + (threadIdx.x >> 6);
    if (node >= n) return;
    const int lane = threadIdx.x & 63;
    const int beg = rowptr[node], deg = rowptr[node + 1] - beg;
    if (deg <= 1) return;
    if (deg > 64) {
        if (lane == 0) {   // unreachable in practice; determinism safety net
            for (int i = beg + 1; i < beg + deg; ++i) {
                int key = csrc[i]; int j2 = i - 1;
                while (j2 >= beg && csrc[j2] > key) { csrc[j2 + 1] = csrc[j2]; --j2; }
                csrc[j2 + 1] = key;
            }
        }
        return;
    }
    int v = lane < deg ? csrc[beg + lane] : 0x7fffffff;
#pragma unroll
    for (int k = 2; k <= 64; k <<= 1) {
#pragma unroll
        for (int j = k >> 1; j > 0; j >>= 1) {
            int pv = __shfl_xor(v, j);
            bool up = (lane & k) == 0;
            bool takeMin = ((lane & j) == 0) == up;
            int mn = min(v, pv), mx = max(v, pv);
            v = takeMin ? mn : mx;
        }
    }
    if (lane < deg) csrc[beg + lane] = v;
}

// ------- layer-1 aggregation: wave/node, single exp chain + ds_bpermute for straddle lanes.
// Only lanes 12 and 37 span two heads; they pull the second head's p from lanes 13/40
// (bit-identical to computing it locally). Emits hcat as bf16 hi/lo pairs (gemm2 A operand).
__global__ __launch_bounds__(256) void gat_agg1(
    const unsigned short* __restrict__ Hb, const float* __restrict__ asrc,
    const float* __restrict__ adst, const int* __restrict__ rowptr,
    const int* __restrict__ csrc, const float* __restrict__ b1,
    unsigned short* __restrict__ hcat_hi, unsigned short* __restrict__ hcat_lo, int n) {
    int node = blockIdx.x * 4 + (threadIdx.x >> 6);
    if (node >= n) return;
    const int lane = threadIdx.x & 63;
    const int beg = rowptr[node], end = rowptr[node + 1];
    const bool act = lane < C1CH;
    const int ch0 = act ? lane * 4 : 0;          // clamped for safe addressing
    const int hd0 = ch0 / C1CH;
    const bool c1 = ((ch0 + 1) / C1CH) == hd0;
    const bool c2 = ((ch0 + 2) / C1CH) == hd0;
    const float4 adv = reinterpret_cast<const float4*>(adst)[node];
    const float ad0 = SEL4(hd0, adv.x, adv.y, adv.z, adv.w);
    // bpermute byte address: lane 12 reads lane 13 (head 1), lane 37 reads lane 40 (head 3)
    const int bperm = (lane == 12 ? 13 : lane == 37 ? 40 : lane) << 2;

    float ssum0 = 0.f, ssum3 = 0.f;
    float a0 = 0.f, a1 = 0.f, a2 = 0.f, a3 = 0.f;

#define AGG1_EDGE(ev, hv)                                                       \
    {                                                                           \
        float p0 = __expf(lrelu((ev) + ad0));                                   \
        float p3 = __int_as_float(                                              \
            __builtin_amdgcn_ds_bpermute(bperm, __float_as_int(p0)));           \
        ssum0 += p0; ssum3 += p3;                                               \
        float p1 = c1 ? p0 : p3, p2 = c2 ? p0 : p3;                             \
        a0 += p0 * b2f((hv).x);                                                 \
        a1 += p1 * b2f((hv).y);                                                 \
        a2 += p2 * b2f((hv).z);                                                 \
        a3 += p3 * b2f((hv).w);                                                 \
    }

    int j = beg;
    for (; j + 4 <= end; j += 4) {
        int sA = csrc[j], sB = csrc[j + 1], sC = csrc[j + 2], sD = csrc[j + 3];
        float eA = asrc[sA * 4 + hd0], eB = asrc[sB * 4 + hd0];
        float eC = asrc[sC * 4 + hd0], eD = asrc[sD * 4 + hd0];
        ushort4 hA = *reinterpret_cast<const ushort4*>(Hb + (size_t)sA * HID + ch0);
        ushort4 hB = *reinterpret_cast<const ushort4*>(Hb + (size_t)sB * HID + ch0);
        ushort4 hC = *reinterpret_cast<const ushort4*>(Hb + (size_t)sC * HID + ch0);
        ushort4 hD = *reinterpret_cast<const ushort4*>(Hb + (size_t)sD * HID + ch0);
        AGG1_EDGE(eA, hA)
        AGG1_EDGE(eB, hB)
        AGG1_EDGE(eC, hC)
        AGG1_EDGE(eD, hD)
    }
    for (; j < end; ++j) {
        int sA = csrc[j];
        float eA = asrc[sA * 4 + hd0];
        ushort4 hA = *reinterpret_cast<const ushort4*>(Hb + (size_t)sA * HID + ch0);
        AGG1_EDGE(eA, hA)
    }
#undef AGG1_EDGE

    if (act) {
        const float n0 = ssum0 + 1e-16f, n3 = ssum3 + 1e-16f;
        const float n1 = c1 ? n0 : n3, n2 = c2 ? n0 : n3;
        float4 bv = reinterpret_cast<const float4*>(b1)[lane];
        float v0 = a0 / n0 + bv.x;
        float v1 = a1 / n1 + bv.y;
        float v2 = a2 / n2 + bv.z;
        float v3 = a3 / n3 + bv.w;
        v0 = v0 > 0.f ? v0 : __expf(v0) - 1.f;
        v1 = v1 > 0.f ? v1 : __expf(v1) - 1.f;
        v2 = v2 > 0.f ? v2 : __expf(v2) - 1.f;
        v3 = v3 > 0.f ? v3 : __expf(v3) - 1.f;
        unsigned short h0, l0, h1, l1, h2, l2, h3, l3;
        split_bf16(v0, h0, l0); split_bf16(v1, h1, l1);
        split_bf16(v2, h2, l2); split_bf16(v3, h3, l3);
        *reinterpret_cast<ushort4*>(hcat_hi + (size_t)node * KPAD2 + ch0) = make_ushort4(h0, h1, h2, h3);
        *reinterpret_cast<ushort4*>(hcat_lo + (size_t)node * KPAD2 + ch0) = make_ushort4(l0, l1, l2, l3);
    } else if (lane < 56) {  // zero the K-pad cols 200..223 (6 lanes x 4)
        int off = HID + (lane - C1CH) * 4;
        *reinterpret_cast<ushort4*>(hcat_hi + (size_t)node * KPAD2 + off) = make_ushort4(0, 0, 0, 0);
        *reinterpret_cast<ushort4*>(hcat_lo + (size_t)node * KPAD2 + off) = make_ushort4(0, 0, 0, 0);
    }
}

// ------- layer-2 aggregation: wave/node, single pass, fused bias + log_softmax -------
__global__ __launch_bounds__(256) void gat_agg2(
    const unsigned short* __restrict__ Hb, const float* __restrict__ asrc,
    const float* __restrict__ adst, const int* __restrict__ rowptr,
    const int* __restrict__ csrc, const float* __restrict__ b2,
    float* __restrict__ outp, int n) {
    int node = blockIdx.x * 4 + (threadIdx.x >> 6);
    if (node >= n) return;
    const int lane = threadIdx.x & 63;
    const int beg = rowptr[node], end = rowptr[node + 1];
    const float ad = adst[node];
    const bool act = lane < FOUT;
    const int lc = act ? lane : 0;   // clamped channel for safe loads

    float ssum = 0.f, acc = 0.f;

#define AGG2_EDGE(ev, hv)                                    \
    {                                                        \
        float p = __expf(lrelu((ev) + ad));                  \
        ssum += p;                                           \
        acc += p * b2f(hv);                                  \
    }

    int j = beg;
    for (; j + 4 <= end; j += 4) {
        int sA = csrc[j], sB = csrc[j + 1], sC = csrc[j + 2], sD = csrc[j + 3];
        float eA = asrc[sA], eB = asrc[sB], eC = asrc[sC], eD = asrc[sD];
        unsigned short hA = Hb[(size_t)sA * FOUT + lc];
        unsigned short hB = Hb[(size_t)sB * FOUT + lc];
        unsigned short hC = Hb[(size_t)sC * FOUT + lc];
        unsigned short hD = Hb[(size_t)sD * FOUT + lc];
        AGG2_EDGE(eA, hA)
        AGG2_EDGE(eB, hB)
        AGG2_EDGE(eC, hC)
        AGG2_EDGE(eD, hD)
    }
    for (; j < end; ++j) {
        int sA = csrc[j];
        float eA = asrc[sA];
        unsigned short hA = Hb[(size_t)sA * FOUT + lc];
        AGG2_EDGE(eA, hA)
    }
#undef AGG2_EDGE

    float val = act ? (acc / (ssum + 1e-16f) + b2[lane]) : -1e30f;
    float mx = val;
#pragma unroll
    for (int off = 32; off >= 1; off >>= 1) mx = fmaxf(mx, __shfl_xor(mx, off));
    float ex = act ? __expf(val - mx) : 0.f;
    float z = ex;
#pragma unroll
    for (int off = 32; off >= 1; off >>= 1) z += __shfl_xor(z, off);
    if (act) outp[(size_t)node * FOUT + lane] = val - mx - __logf(z);
}

extern "C" void kernel_launch(void* const* d_in, const int* in_sizes, int n_in,
                              void* d_out, int out_size, void* d_ws, size_t ws_size,
                              hipStream_t stream) {
    const float* x        = (const float*)d_in[0];
    const int*   esrc     = (const int*)d_in[1];
    const int*   edst     = (const int*)d_in[2];
    const float* W1       = (const float*)d_in[3];
    const float* att_src1 = (const float*)d_in[4];
    const float* att_dst1 = (const float*)d_in[5];
    const float* b1       = (const float*)d_in[6];
    const float* W2       = (const float*)d_in[7];
    const float* att_src2 = (const float*)d_in[8];
    const float* att_dst2 = (const float*)d_in[9];
    const float* b2       = (const float*)d_in[10];
    float* out = (float*)d_out;

    const int n = NODES;
    const int e = in_sizes[1];
    const int nb = (n + 1023) / 1024;

    char* p = (char*)d_ws;
    auto alloc = [&](size_t bytes) -> char* {
        char* q = p;
        p += (bytes + 255) & ~(size_t)255;
        return q;
    };
    unsigned short* w1hi    = (unsigned short*)alloc((size_t)NPAD1 * FIN * 2);
    unsigned short* w1lo    = (unsigned short*)alloc((size_t)NPAD1 * FIN * 2);
    unsigned short* w2hi    = (unsigned short*)alloc((size_t)NPAD2 * KPAD2 * 2);
    unsigned short* w2lo    = (unsigned short*)alloc((size_t)NPAD2 * KPAD2 * 2);
    unsigned short* h1b     = (unsigned short*)alloc((size_t)n * HID * 2);
    unsigned short* hcat_hi = (unsigned short*)alloc((size_t)n * KPAD2 * 2);
    unsigned short* hcat_lo = (unsigned short*)alloc((size_t)n * KPAD2 * 2);
    unsigned short* h2b     = (unsigned short*)alloc((size_t)n * FOUT * 2);
    float* as1    = (float*)alloc((size_t)n * NH1 * 4);
    float* ad1    = (float*)alloc((size_t)n * NH1 * 4);
    float* as2    = (float*)alloc((size_t)n * 4);
    float* ad2    = (float*)alloc((size_t)n * 4);
    int*   deg    = (int*)alloc((size_t)n * 4);
    int*   incl   = (int*)alloc((size_t)n * 4);
    int*   rowptr = (int*)alloc((size_t)(n + 1) * 4);
    int*   cursor = (int*)alloc((size_t)n * 4);
    int*   csrc   = (int*)alloc((size_t)e * 4);
    int*   bsum   = (int*)alloc((size_t)nb * 4);
    int*   boffs  = (int*)alloc((size_t)nb * 4);
    if ((size_t)(p - (char*)d_ws) > ws_size) {
        fprintf(stderr, "kernel_launch: ws too small (%zu needed, %zu given)\n",
                (size_t)(p - (char*)d_ws), ws_size);
        return;
    }

    // CSR build + canonical segment order (deterministic output every call)
    hipMemsetAsync(deg, 0, (size_t)n * 4, stream);
    hist_kernel<<<(e + 255) / 256, 256, 0, stream>>>(edst, deg, e);
    blockscan_kernel<<<nb, 1024, 0, stream>>>(deg, incl, bsum, n);
    sumscan_kernel<<<1, 64, 0, stream>>>(bsum, boffs, nb);
    applyscan_kernel<<<(n + 255) / 256, 256, 0, stream>>>(incl, boffs, deg, rowptr, cursor, n);
    scatter_kernel<<<(e + 255) / 256, 256, 0, stream>>>(esrc, edst, cursor, csrc, e);
    sort_segments<<<(n + 3) / 4, 256, 0, stream>>>(rowptr, csrc, n);

    // weight prep (hi/lo split)
    prep_w1<<<(NPAD1 * FIN + 255) / 256, 256, 0, stream>>>(W1, w1hi, w1lo);
    prep_w2<<<(NPAD2 * KPAD2 + 255) / 256, 256, 0, stream>>>(W2, w2hi, w2lo);

    // layer 1
    gemm1_mfma<<<(n + 63) / 64, 256, 0, stream>>>(x, w1hi, w1lo, att_src1, att_dst1, h1b, as1, ad1, n);
    gat_agg1<<<(n + 3) / 4, 256, 0, stream>>>(h1b, as1, ad1, rowptr, csrc, b1, hcat_hi, hcat_lo, n);

    // layer 2
    gemm2_mfma<<<(n + 63) / 64, 256, 0, stream>>>(hcat_hi, hcat_lo, w2hi, w2lo, att_src2, att_dst2, h2b, as2, ad2, n);
    gat_agg2<<<(n + 3) / 4, 256, 0, stream>>>(h2b, as2, ad2, rowptr, csrc, b2, out, n);
}